// Round 1
// baseline (3797.135 us; speedup 1.0000x reference)
//
#include <hip/hip_runtime.h>

typedef unsigned short u16;
typedef __attribute__((ext_vector_type(8))) short short8;
typedef __attribute__((ext_vector_type(4))) float f32x4;
typedef __attribute__((ext_vector_type(4))) u16 u16x4;

#define LSEQ   1024
#define DMODEL 1024
#define NHEAD  16
#define DHEAD  64
#define DFF    4096
#define NLAYER 12
#define NVOCAB 32000

__device__ __forceinline__ u16 f2b(float f) {
  union { float f; unsigned u; } x; x.f = f;
  unsigned r = x.u + 0x7fffu + ((x.u >> 16) & 1u);   // RNE
  return (u16)(r >> 16);
}

__device__ __forceinline__ f32x4 mfma16(short8 a, short8 b, f32x4 c) {
  return __builtin_amdgcn_mfma_f32_16x16x32_bf16(a, b, c, 0, 0, 0);
}

// ---------------- embedding + positional encoding ----------------
// x[l,d] = 2*emb[tok[l],d]*sqrt(3*D) + pe(l,d);  pe: d=2p -> sin(l*10000^(-2p/D)), d=2p+1 -> cos
__global__ __launch_bounds__(256) void embed_k(const int* __restrict__ tok,
    const float* __restrict__ emb, float* __restrict__ x, u16* __restrict__ xb)
{
  const int l = blockIdx.x;
  const int d0 = threadIdx.x * 4;
  const int t = tok[l];
  const float lf = (float)l;
  float o[4]; u16 obv[4];
#pragma unroll
  for (int j = 0; j < 4; ++j) {
    int d = d0 + j;
    int p = d >> 1;
    float ang = lf * powf(10000.0f, -(float)(2 * p) / 1024.0f);
    float pe = (d & 1) ? cosf(ang) : sinf(ang);
    float val = 2.0f * emb[(size_t)t * DMODEL + d] * 55.42562584220407f + pe; // sqrt(3072)
    o[j] = val; obv[j] = f2b(val);
  }
  *reinterpret_cast<float4*>(x + (size_t)l * DMODEL + d0) = make_float4(o[0], o[1], o[2], o[3]);
  u16x4 vb = { obv[0], obv[1], obv[2], obv[3] };
  *reinterpret_cast<u16x4*>(xb + (size_t)l * DMODEL + d0) = vb;
}

// ---------------- residual-add + LayerNorm (writes f32 x and bf16 xb) ----------------
__global__ __launch_bounds__(256) void ln_k(const float* __restrict__ xin,
    const float* __restrict__ yin, const float* __restrict__ s, const float* __restrict__ b,
    float* __restrict__ xout, u16* __restrict__ xbout)
{
  const int row = blockIdx.x, tid = threadIdx.x;
  const int d0 = tid * 4;
  float4 xv = *reinterpret_cast<const float4*>(xin + (size_t)row * DMODEL + d0);
  float4 yv = *reinterpret_cast<const float4*>(yin + (size_t)row * DMODEL + d0);
  float t0 = xv.x + yv.x, t1 = xv.y + yv.y, t2 = xv.z + yv.z, t3 = xv.w + yv.w;
  float sum = t0 + t1 + t2 + t3;
  float sq  = t0 * t0 + t1 * t1 + t2 * t2 + t3 * t3;
#pragma unroll
  for (int d = 1; d < 64; d <<= 1) { sum += __shfl_xor(sum, d); sq += __shfl_xor(sq, d); }
  __shared__ float ssum[4], ssq[4];
  const int wid = tid >> 6;
  if ((tid & 63) == 0) { ssum[wid] = sum; ssq[wid] = sq; }
  __syncthreads();
  sum = ssum[0] + ssum[1] + ssum[2] + ssum[3];
  sq  = ssq[0] + ssq[1] + ssq[2] + ssq[3];
  const float mu = sum * (1.0f / 1024.0f);
  const float var = sq * (1.0f / 1024.0f) - mu * mu;
  const float rstd = rsqrtf(var + 1e-5f);
  float4 sv = *reinterpret_cast<const float4*>(s + d0);
  float4 bv = *reinterpret_cast<const float4*>(b + d0);
  float o0 = (t0 - mu) * rstd * sv.x + bv.x;
  float o1 = (t1 - mu) * rstd * sv.y + bv.y;
  float o2 = (t2 - mu) * rstd * sv.z + bv.z;
  float o3 = (t3 - mu) * rstd * sv.w + bv.w;
  *reinterpret_cast<float4*>(xout + (size_t)row * DMODEL + d0) = make_float4(o0, o1, o2, o3);
  u16x4 vb = { f2b(o0), f2b(o1), f2b(o2), f2b(o3) };
  *reinterpret_cast<u16x4*>(xbout + (size_t)row * DMODEL + d0) = vb;
}

// ---------------- generic bf16-MFMA GEMM ----------------
// C[M,N] = act(A[M,K](bf16) * B[K,N](f32->bf16) + bias)
// BMODE: 0 = row-major B[k*ldb+n]; 1 = fused QKV (B sel by n>>10, per-head [D,64]);
//        2 = NT (B[n*ldb+k], K-contiguous; emb for tied projection)
// OUTMODE: 0 = f32 row-major; 1 = bf16 row-major; 2 = QKV triple bf16 [L,1024] x3
template<int BM, int BMODE, bool BIAS, bool RELU, int OUTMODE>
__global__ __launch_bounds__(256) void gemm_k(
    const u16* __restrict__ A, int lda,
    const float* __restrict__ B0, const float* __restrict__ B1, const float* __restrict__ B2,
    const float* __restrict__ bias,
    void* __restrict__ Cv, int ldc, int Ktot, int ldb)
{
  constexpr int PAD = 40;                 // 32 k + 8 pad (keeps 16B alignment, breaks bank stride)
  __shared__ u16 As[BM][PAD];
  __shared__ u16 Bs[128][PAD];            // transposed: Bs[n][k]
  const int tid = threadIdx.x;
  const int lane = tid & 63, wid = tid >> 6;
  const int m0 = blockIdx.y * BM, n0 = blockIdx.x * 128;
  const int wm = (wid >> 1) * (BM / 2);
  const int wn = (wid & 1) * 64;
  constexpr int FM = BM / 32;
  f32x4 acc[FM][4] = {};

  for (int k0 = 0; k0 < Ktot; k0 += 32) {
    // ---- stage A (bf16, already converted) ----
#pragma unroll
    for (int i = 0; i < BM / 64; ++i) {
      int c = tid + i * 256;
      int row = c >> 2, part = c & 3;
      const u16* src = A + (size_t)(m0 + row) * lda + k0 + part * 8;
      *reinterpret_cast<short8*>(&As[row][part * 8]) =
          *reinterpret_cast<const short8*>(src);
    }
    // ---- stage B transposed (f32 -> bf16) ----
    if (BMODE == 2) {
      int n = tid >> 1, kh = (tid & 1) * 16;
      const float* src = B0 + (size_t)(n0 + n) * ldb + k0 + kh;
      u16 tmp[16];
#pragma unroll
      for (int j = 0; j < 16; ++j) tmp[j] = f2b(src[j]);
      *reinterpret_cast<short8*>(&Bs[n][kh])     = *reinterpret_cast<short8*>(&tmp[0]);
      *reinterpret_cast<short8*>(&Bs[n][kh + 8]) = *reinterpret_cast<short8*>(&tmp[8]);
    } else {
      int n = tid & 127, kh = (tid >> 7) * 16;
#pragma unroll
      for (int j = 0; j < 8; ++j) {
        int kk = kh + j * 2;
        float f0, f1;
        if (BMODE == 0) {
          f0 = B0[(size_t)(k0 + kk) * ldb + n0 + n];
          f1 = B0[(size_t)(k0 + kk + 1) * ldb + n0 + n];
        } else {                            // fused QKV: n in [0,3072)
          int nc = n0 + n;
          const float* Bsel = (nc < 1024) ? B0 : (nc < 2048 ? B1 : B2);
          int col = nc & 1023;
          size_t base = (size_t)(col >> 6) * (DMODEL * DHEAD) + (col & 63);
          f0 = Bsel[base + (size_t)(k0 + kk) * DHEAD];
          f1 = Bsel[base + (size_t)(k0 + kk + 1) * DHEAD];
        }
        unsigned pack = (unsigned)f2b(f0) | ((unsigned)f2b(f1) << 16);
        *reinterpret_cast<unsigned*>(&Bs[n][kk]) = pack;
      }
    }
    __syncthreads();
    short8 a[FM], b[4];
#pragma unroll
    for (int fm = 0; fm < FM; ++fm)
      a[fm] = *reinterpret_cast<const short8*>(&As[wm + fm * 16 + (lane & 15)][(lane >> 4) * 8]);
#pragma unroll
    for (int fn = 0; fn < 4; ++fn)
      b[fn] = *reinterpret_cast<const short8*>(&Bs[wn + fn * 16 + (lane & 15)][(lane >> 4) * 8]);
#pragma unroll
    for (int fm = 0; fm < FM; ++fm)
#pragma unroll
      for (int fn = 0; fn < 4; ++fn)
        acc[fm][fn] = mfma16(a[fm], b[fn], acc[fm][fn]);
    __syncthreads();
  }

  // ---- epilogue ----
#pragma unroll
  for (int fm = 0; fm < FM; ++fm) {
#pragma unroll
    for (int fn = 0; fn < 4; ++fn) {
#pragma unroll
      for (int r = 0; r < 4; ++r) {
        int row = m0 + wm + fm * 16 + (lane >> 4) * 4 + r;
        int col = n0 + wn + fn * 16 + (lane & 15);
        float val = acc[fm][fn][r];
        if (BIAS) val += bias[col];
        if (RELU) val = fmaxf(val, 0.0f);
        if (OUTMODE == 0) {
          ((float*)Cv)[(size_t)row * ldc + col] = val;
        } else if (OUTMODE == 1) {
          ((u16*)Cv)[(size_t)row * ldc + col] = f2b(val);
        } else {                            // q/k/v triple, each [L,1024] bf16, contiguous
          int sel = col >> 10, cc = col & 1023;
          ((u16*)Cv)[(size_t)sel * (LSEQ * DMODEL) + (size_t)row * DMODEL + cc] = f2b(val);
        }
      }
    }
  }
}

// ---------------- causal flash attention ----------------
// grid (qt=16, h=16), 4 waves/block; wave = 16 q-rows; kv tiles of 32; online softmax
__global__ __launch_bounds__(256) void attn_k(const u16* __restrict__ q,
    const u16* __restrict__ kmat, const u16* __restrict__ v, u16* __restrict__ o)
{
  __shared__ u16 Ks[32][72];    // [kv][dk]   (64 dk + pad)
  __shared__ u16 Vt[64][40];    // [dv][kv]   (32 kv + pad)
  __shared__ u16 Pl[4][16][40]; // per-wave P [q][kv]
  const int tid = threadIdx.x, lane = tid & 63, wid = tid >> 6;
  const int h = blockIdx.y, qt = blockIdx.x;
  const int qw0 = qt * 64 + wid * 16;
  const int qrow = qw0 + (lane & 15);
  const short8 aq0 = *reinterpret_cast<const short8*>(q + (size_t)qrow * DMODEL + h * DHEAD + (lane >> 4) * 8);
  const short8 aq1 = *reinterpret_cast<const short8*>(q + (size_t)qrow * DMODEL + h * DHEAD + 32 + (lane >> 4) * 8);
  float m_run[4], l_run[4];
  f32x4 oacc[4] = {};
#pragma unroll
  for (int r = 0; r < 4; ++r) { m_run[r] = -1e30f; l_run[r] = 0.0f; }
  const int kvend = qt * 64 + 64;

  for (int kv0 = 0; kv0 < kvend; kv0 += 32) {
    { // stage K [32,64] as-is and V [32,64] transposed
      int kvi = tid >> 3, c8 = (tid & 7) * 8;
      *reinterpret_cast<short8*>(&Ks[kvi][c8]) =
          *reinterpret_cast<const short8*>(kmat + (size_t)(kv0 + kvi) * DMODEL + h * DHEAD + c8);
      short8 vv = *reinterpret_cast<const short8*>(v + (size_t)(kv0 + kvi) * DMODEL + h * DHEAD + c8);
#pragma unroll
      for (int j = 0; j < 8; ++j) Vt[c8 + j][kvi] = (u16)vv[j];
    }
    __syncthreads();

    float sm[2][4];
#pragma unroll
    for (int t2 = 0; t2 < 2; ++t2) {
      short8 bk0 = *reinterpret_cast<const short8*>(&Ks[t2 * 16 + (lane & 15)][(lane >> 4) * 8]);
      short8 bk1 = *reinterpret_cast<const short8*>(&Ks[t2 * 16 + (lane & 15)][32 + (lane >> 4) * 8]);
      f32x4 s4 = {};
      s4 = mfma16(aq0, bk0, s4);
      s4 = mfma16(aq1, bk1, s4);
#pragma unroll
      for (int r = 0; r < 4; ++r) {
        int rowg = qw0 + (lane >> 4) * 4 + r;
        int colg = kv0 + t2 * 16 + (lane & 15);
        float val = s4[r] * 0.03125f;                 // 1/sqrt(D)=1/32 (d_model!)
        sm[t2][r] = (colg <= rowg) ? val : -1e30f;    // causal
      }
    }
    float alpha[4], p0[4], p1[4];
#pragma unroll
    for (int r = 0; r < 4; ++r) {
      float mx = fmaxf(sm[0][r], sm[1][r]);
#pragma unroll
      for (int d = 1; d < 16; d <<= 1) mx = fmaxf(mx, __shfl_xor(mx, d));
      float mn = fmaxf(m_run[r], mx);
      alpha[r] = __expf(m_run[r] - mn);
      p0[r] = __expf(sm[0][r] - mn);
      p1[r] = __expf(sm[1][r] - mn);
      float ps = p0[r] + p1[r];
#pragma unroll
      for (int d = 1; d < 16; d <<= 1) ps += __shfl_xor(ps, d);
      l_run[r] = l_run[r] * alpha[r] + ps;
      m_run[r] = mn;
    }
#pragma unroll
    for (int fn = 0; fn < 4; ++fn) {
      f32x4 t = oacc[fn];
      t[0] *= alpha[0]; t[1] *= alpha[1]; t[2] *= alpha[2]; t[3] *= alpha[3];
      oacc[fn] = t;
    }
    // P -> LDS (transpose to A-fragment layout), then PV
#pragma unroll
    for (int r = 0; r < 4; ++r) {
      int rit = (lane >> 4) * 4 + r;
      Pl[wid][rit][lane & 15]      = f2b(p0[r]);
      Pl[wid][rit][16 + (lane & 15)] = f2b(p1[r]);
    }
    short8 pa = *reinterpret_cast<const short8*>(&Pl[wid][lane & 15][(lane >> 4) * 8]);
#pragma unroll
    for (int fn = 0; fn < 4; ++fn) {
      short8 bv = *reinterpret_cast<const short8*>(&Vt[fn * 16 + (lane & 15)][(lane >> 4) * 8]);
      oacc[fn] = mfma16(pa, bv, oacc[fn]);
    }
    __syncthreads();
  }
#pragma unroll
  for (int fn = 0; fn < 4; ++fn) {
#pragma unroll
    for (int r = 0; r < 4; ++r) {
      int row = qw0 + (lane >> 4) * 4 + r;
      float val = oacc[fn][r] / l_run[r];
      o[(size_t)row * DMODEL + h * DHEAD + fn * 16 + (lane & 15)] = f2b(val);
    }
  }
}

// ---------------- launch ----------------
extern "C" void kernel_launch(void* const* d_in, const int* in_sizes, int n_in,
                              void* d_out, int out_size, void* d_ws, size_t ws_size,
                              hipStream_t stream) {
  (void)in_sizes; (void)n_in; (void)out_size; (void)ws_size;
  const int*   tok    = (const int*)d_in[0];
  const float* emb    = (const float*)d_in[1];
  const float* finalb = (const float*)d_in[2];
  const float* Wq     = (const float*)d_in[3];
  const float* Wk     = (const float*)d_in[4];
  const float* Wv     = (const float*)d_in[5];
  const float* Wo     = (const float*)d_in[6];
  const float* ln1s   = (const float*)d_in[7];
  const float* ln1b   = (const float*)d_in[8];
  const float* W1     = (const float*)d_in[9];
  const float* b1     = (const float*)d_in[10];
  const float* W2     = (const float*)d_in[11];
  const float* b2     = (const float*)d_in[12];
  const float* ln2s   = (const float*)d_in[13];
  const float* ln2b   = (const float*)d_in[14];
  float* out = (float*)d_out;

  // workspace: x(f32 4MB) y(f32 4MB) xb/q/k/v/o(bf16 2MB each) h1(bf16 8MB) = 26 MB
  float* x  = (float*)d_ws;
  float* y  = x + LSEQ * DMODEL;
  u16* xb   = (u16*)(y + LSEQ * DMODEL);
  u16* qb   = xb + LSEQ * DMODEL;
  u16* kb   = qb + LSEQ * DMODEL;
  u16* vb   = kb + LSEQ * DMODEL;
  u16* ob   = vb + LSEQ * DMODEL;
  u16* h1   = ob + LSEQ * DMODEL;

  embed_k<<<LSEQ, 256, 0, stream>>>(tok, emb, x, xb);

  for (int l = 0; l < NLAYER; ++l) {
    const float* wq  = Wq + (size_t)l * NHEAD * DMODEL * DHEAD;
    const float* wk  = Wk + (size_t)l * NHEAD * DMODEL * DHEAD;
    const float* wv  = Wv + (size_t)l * NHEAD * DMODEL * DHEAD;
    const float* wo  = Wo + (size_t)l * DMODEL * DMODEL;
    const float* w1  = W1 + (size_t)l * DMODEL * DFF;
    const float* b1l = b1 + (size_t)l * DFF;
    const float* w2  = W2 + (size_t)l * DFF * DMODEL;
    const float* b2l = b2 + (size_t)l * DMODEL;

    // fused QKV: [1024,1024] x [1024,3072] -> q,k,v bf16
    gemm_k<128, 1, false, false, 2><<<dim3(24, 8), 256, 0, stream>>>(
        xb, DMODEL, wq, wk, wv, nullptr, qb, DMODEL, DMODEL, DHEAD);
    // causal attention -> o bf16 [1024,1024]
    attn_k<<<dim3(16, 16), 256, 0, stream>>>(qb, kb, vb, ob);
    // o @ Wo -> y f32
    gemm_k<64, 0, false, false, 0><<<dim3(8, 16), 256, 0, stream>>>(
        ob, DMODEL, wo, nullptr, nullptr, nullptr, y, DMODEL, DMODEL, DMODEL);
    // x = LN(x + y)
    ln_k<<<LSEQ, 256, 0, stream>>>(x, y, ln1s + (size_t)l * DMODEL, ln1b + (size_t)l * DMODEL, x, xb);
    // h1 = relu(x @ W1 + b1) bf16
    gemm_k<128, 0, true, true, 1><<<dim3(32, 8), 256, 0, stream>>>(
        xb, DMODEL, w1, nullptr, nullptr, b1l, h1, DFF, DMODEL, DFF);
    // y = h1 @ W2 + b2 f32
    gemm_k<64, 0, true, false, 0><<<dim3(8, 16), 256, 0, stream>>>(
        h1, DFF, w2, nullptr, nullptr, b2l, y, DMODEL, DFF, DMODEL);
    // x = LN(x + y)
    ln_k<<<LSEQ, 256, 0, stream>>>(x, y, ln2s + (size_t)l * DMODEL, ln2b + (size_t)l * DMODEL, x, xb);
  }

  // logits = x @ emb^T + final_b  (NT GEMM, N=32000)
  gemm_k<128, 2, true, false, 0><<<dim3(250, 8), 256, 0, stream>>>(
      xb, DMODEL, emb, nullptr, nullptr, finalb, out, NVOCAB, DMODEL, DMODEL);
}

// Round 2
// 2378.997 us; speedup vs baseline: 1.5961x; 1.5961x over previous
//
#include <hip/hip_runtime.h>

typedef unsigned short u16;
typedef __attribute__((ext_vector_type(8))) short short8;
typedef __attribute__((ext_vector_type(4))) float f32x4;
typedef __attribute__((ext_vector_type(4))) u16 u16x4;

#define LSEQ   1024
#define DMODEL 1024
#define NHEAD  16
#define DHEAD  64
#define DFF    4096
#define NLAYER 12
#define NVOCAB 32000

__device__ __forceinline__ u16 f2b(float f) {
  union { float f; unsigned u; } x; x.f = f;
  unsigned r = x.u + 0x7fffu + ((x.u >> 16) & 1u);   // RNE
  return (u16)(r >> 16);
}

__device__ __forceinline__ f32x4 mfma16(short8 a, short8 b, f32x4 c) {
  return __builtin_amdgcn_mfma_f32_16x16x32_bf16(a, b, c, 0, 0, 0);
}

// async global->LDS, 16B per lane. LDS dest = wave-uniform base + lane*16.
__device__ __forceinline__ void gload16(const u16* g, u16* l) {
  __builtin_amdgcn_global_load_lds(
      (const __attribute__((address_space(1))) void*)g,
      (__attribute__((address_space(3))) void*)l, 16, 0, 0);
}

// ---------------- embedding + positional encoding ----------------
__global__ __launch_bounds__(256) void embed_k(const int* __restrict__ tok,
    const float* __restrict__ emb, float* __restrict__ x, u16* __restrict__ xb)
{
  const int l = blockIdx.x;
  const int d0 = threadIdx.x * 4;
  const int t = tok[l];
  const float lf = (float)l;
  float o[4]; u16 obv[4];
#pragma unroll
  for (int j = 0; j < 4; ++j) {
    int d = d0 + j;
    int p = d >> 1;
    float ang = lf * powf(10000.0f, -(float)(2 * p) / 1024.0f);
    float pe = (d & 1) ? cosf(ang) : sinf(ang);
    float val = 2.0f * emb[(size_t)t * DMODEL + d] * 55.42562584220407f + pe; // sqrt(3072)
    o[j] = val; obv[j] = f2b(val);
  }
  *reinterpret_cast<float4*>(x + (size_t)l * DMODEL + d0) = make_float4(o[0], o[1], o[2], o[3]);
  u16x4 vb = { obv[0], obv[1], obv[2], obv[3] };
  *reinterpret_cast<u16x4*>(xb + (size_t)l * DMODEL + d0) = vb;
}

// ---------------- residual-add + LayerNorm ----------------
__global__ __launch_bounds__(256) void ln_k(const float* __restrict__ xin,
    const float* __restrict__ yin, const float* __restrict__ s, const float* __restrict__ b,
    float* __restrict__ xout, u16* __restrict__ xbout)
{
  const int row = blockIdx.x, tid = threadIdx.x;
  const int d0 = tid * 4;
  float4 xv = *reinterpret_cast<const float4*>(xin + (size_t)row * DMODEL + d0);
  float4 yv = *reinterpret_cast<const float4*>(yin + (size_t)row * DMODEL + d0);
  float t0 = xv.x + yv.x, t1 = xv.y + yv.y, t2 = xv.z + yv.z, t3 = xv.w + yv.w;
  float sum = t0 + t1 + t2 + t3;
  float sq  = t0 * t0 + t1 * t1 + t2 * t2 + t3 * t3;
#pragma unroll
  for (int d = 1; d < 64; d <<= 1) { sum += __shfl_xor(sum, d); sq += __shfl_xor(sq, d); }
  __shared__ float ssum[4], ssq[4];
  const int wid = tid >> 6;
  if ((tid & 63) == 0) { ssum[wid] = sum; ssq[wid] = sq; }
  __syncthreads();
  sum = ssum[0] + ssum[1] + ssum[2] + ssum[3];
  sq  = ssq[0] + ssq[1] + ssq[2] + ssq[3];
  const float mu = sum * (1.0f / 1024.0f);
  const float var = sq * (1.0f / 1024.0f) - mu * mu;
  const float rstd = rsqrtf(var + 1e-5f);
  float4 sv = *reinterpret_cast<const float4*>(s + d0);
  float4 bv = *reinterpret_cast<const float4*>(b + d0);
  float o0 = (t0 - mu) * rstd * sv.x + bv.x;
  float o1 = (t1 - mu) * rstd * sv.y + bv.y;
  float o2 = (t2 - mu) * rstd * sv.z + bv.z;
  float o3 = (t3 - mu) * rstd * sv.w + bv.w;
  *reinterpret_cast<float4*>(xout + (size_t)row * DMODEL + d0) = make_float4(o0, o1, o2, o3);
  u16x4 vb = { f2b(o0), f2b(o1), f2b(o2), f2b(o3) };
  *reinterpret_cast<u16x4*>(xbout + (size_t)row * DMODEL + d0) = vb;
}

// ---------------- transpose-convert: f32 in[R][C] -> bf16 out[C(+obase)][R] ----------------
// grid (C/64, R/64, Z); batched along z (independent matrices, out rows stacked by C)
__global__ __launch_bounds__(256) void tconv_k(const float* __restrict__ in, u16* __restrict__ out,
                                               int R, int C, int obase, int zstride)
{
  __shared__ float t[64][65];
  const int rt = blockIdx.y * 64, ct = blockIdx.x * 64;
  in += (size_t)blockIdx.z * zstride;
  const int tr = threadIdx.x >> 4, tc = threadIdx.x & 15;
#pragma unroll
  for (int i = 0; i < 4; ++i) {
    int r = i * 16 + tr;
    float4 v = *reinterpret_cast<const float4*>(in + (size_t)(rt + r) * C + ct + tc * 4);
    t[r][tc * 4 + 0] = v.x; t[r][tc * 4 + 1] = v.y;
    t[r][tc * 4 + 2] = v.z; t[r][tc * 4 + 3] = v.w;
  }
  __syncthreads();
  const int orow0 = obase + blockIdx.z * C + ct;
#pragma unroll
  for (int i = 0; i < 4; ++i) {
    int c = i * 16 + tr;
    u16x4 o;
    o[0] = f2b(t[tc * 4 + 0][c]); o[1] = f2b(t[tc * 4 + 1][c]);
    o[2] = f2b(t[tc * 4 + 2][c]); o[3] = f2b(t[tc * 4 + 3][c]);
    *reinterpret_cast<u16x4*>(out + (size_t)(orow0 + c) * R + rt + tc * 4) = o;
  }
}

// ---------------- elementwise convert f32 -> bf16 (emb, already N-major) ----------------
__global__ __launch_bounds__(256) void ec_k(const float* __restrict__ in, u16* __restrict__ out)
{
  const size_t i = ((size_t)blockIdx.x * 256 + threadIdx.x) * 8;
  float4 a = *reinterpret_cast<const float4*>(in + i);
  float4 b = *reinterpret_cast<const float4*>(in + i + 4);
  short8 o;
  o[0] = f2b(a.x); o[1] = f2b(a.y); o[2] = f2b(a.z); o[3] = f2b(a.w);
  o[4] = f2b(b.x); o[5] = f2b(b.y); o[6] = f2b(b.z); o[7] = f2b(b.w);
  *reinterpret_cast<short8*>(out + i) = o;
}

// ---------------- bf16 MFMA GEMM, m97 structure ----------------
// C[M,N] = act(A[M,K] * Bt[N,K]^T + bias); A bf16 row-major, Bt = B^T bf16 (BSRC=0) or f32 (BSRC=1)
// OUTMODE: 0 = f32; 1 = bf16; 2 = QKV triple bf16 [L,1024] x3
template<int BM, int BN, int BSRC, bool BIAS, bool RELU, int OUTMODE>
__global__ __launch_bounds__(256) void gemm_bt(
    const u16* __restrict__ A, int lda,
    const void* __restrict__ Bp, int ldb,
    const float* __restrict__ bias,
    void* __restrict__ Cv, int ldc, int Ktot)
{
  __shared__ u16 As[BM * 32];
  __shared__ u16 Bs[BN * 32];
  const int tid = threadIdx.x, lane = tid & 63, wid = tid >> 6;
  const int m0 = blockIdx.y * BM, n0 = blockIdx.x * BN;
  constexpr int FM = BM / 32, FN = BN / 32;
  const int wm = (wid >> 1) * (BM / 2), wn = (wid & 1) * (BN / 2);
  const u16* Bt = (const u16*)Bp;
  const float* Bf = (const float*)Bp;
  f32x4 acc[FM][FN] = {};

  for (int k0 = 0; k0 < Ktot; k0 += 32) {
    // ---- stage A via global_load_lds (linear LDS [BM][32]) ----
#pragma unroll
    for (int i = 0; i < BM / 64; ++i) {
      int c = i * 256 + wid * 64 + lane;          // chunk id, 16B each
      int row = c >> 2, part = c & 3;
      gload16(A + (size_t)(m0 + row) * lda + k0 + part * 8,
              &As[(i * 256 + wid * 64) * 8]);     // wave-uniform LDS base
    }
    // ---- stage B ----
    if (BSRC == 0) {
#pragma unroll
      for (int i = 0; i < BN / 64; ++i) {
        int c = i * 256 + wid * 64 + lane;
        int row = c >> 2, part = c & 3;
        gload16(Bt + (size_t)(n0 + row) * ldb + k0 + part * 8,
                &Bs[(i * 256 + wid * 64) * 8]);
      }
    } else {                                      // f32 B^T, reg-stage + convert (BN must be 128)
      int row = tid >> 1, kh = (tid & 1) * 16;
      const float* src = Bf + (size_t)(n0 + row) * ldb + k0 + kh;
      float4 v0 = *reinterpret_cast<const float4*>(src);
      float4 v1 = *reinterpret_cast<const float4*>(src + 4);
      float4 v2 = *reinterpret_cast<const float4*>(src + 8);
      float4 v3 = *reinterpret_cast<const float4*>(src + 12);
      short8 p0, p1;
      p0[0] = f2b(v0.x); p0[1] = f2b(v0.y); p0[2] = f2b(v0.z); p0[3] = f2b(v0.w);
      p0[4] = f2b(v1.x); p0[5] = f2b(v1.y); p0[6] = f2b(v1.z); p0[7] = f2b(v1.w);
      p1[0] = f2b(v2.x); p1[1] = f2b(v2.y); p1[2] = f2b(v2.z); p1[3] = f2b(v2.w);
      p1[4] = f2b(v3.x); p1[5] = f2b(v3.y); p1[6] = f2b(v3.z); p1[7] = f2b(v3.w);
      *reinterpret_cast<short8*>(&Bs[row * 32 + kh])     = p0;
      *reinterpret_cast<short8*>(&Bs[row * 32 + kh + 8]) = p1;
    }
    __syncthreads();
    short8 a[FM], b[FN];
#pragma unroll
    for (int fm = 0; fm < FM; ++fm)
      a[fm] = *reinterpret_cast<const short8*>(&As[(wm + fm * 16 + (lane & 15)) * 32 + (lane >> 4) * 8]);
#pragma unroll
    for (int fn = 0; fn < FN; ++fn)
      b[fn] = *reinterpret_cast<const short8*>(&Bs[(wn + fn * 16 + (lane & 15)) * 32 + (lane >> 4) * 8]);
#pragma unroll
    for (int fm = 0; fm < FM; ++fm)
#pragma unroll
      for (int fn = 0; fn < FN; ++fn)
        acc[fm][fn] = mfma16(a[fm], b[fn], acc[fm][fn]);
    __syncthreads();
  }

  // ---- epilogue ----
#pragma unroll
  for (int fm = 0; fm < FM; ++fm) {
#pragma unroll
    for (int fn = 0; fn < FN; ++fn) {
#pragma unroll
      for (int r = 0; r < 4; ++r) {
        int row = m0 + wm + fm * 16 + (lane >> 4) * 4 + r;
        int col = n0 + wn + fn * 16 + (lane & 15);
        float val = acc[fm][fn][r];
        if (BIAS) val += bias[col];
        if (RELU) val = fmaxf(val, 0.0f);
        if (OUTMODE == 0) {
          ((float*)Cv)[(size_t)row * ldc + col] = val;
        } else if (OUTMODE == 1) {
          ((u16*)Cv)[(size_t)row * ldc + col] = f2b(val);
        } else {
          int sel = col >> 10, cc = col & 1023;
          ((u16*)Cv)[(size_t)sel * (LSEQ * DMODEL) + (size_t)row * DMODEL + cc] = f2b(val);
        }
      }
    }
  }
}

// ---------------- causal flash attention ----------------
__global__ __launch_bounds__(256) void attn_k(const u16* __restrict__ q,
    const u16* __restrict__ kmat, const u16* __restrict__ v, u16* __restrict__ o)
{
  __shared__ u16 Ks[32][72];
  __shared__ u16 Vt[64][40];
  __shared__ u16 Pl[4][16][40];
  const int tid = threadIdx.x, lane = tid & 63, wid = tid >> 6;
  const int h = blockIdx.y, qt = blockIdx.x;
  const int qw0 = qt * 64 + wid * 16;
  const int qrow = qw0 + (lane & 15);
  const short8 aq0 = *reinterpret_cast<const short8*>(q + (size_t)qrow * DMODEL + h * DHEAD + (lane >> 4) * 8);
  const short8 aq1 = *reinterpret_cast<const short8*>(q + (size_t)qrow * DMODEL + h * DHEAD + 32 + (lane >> 4) * 8);
  float m_run[4], l_run[4];
  f32x4 oacc[4] = {};
#pragma unroll
  for (int r = 0; r < 4; ++r) { m_run[r] = -1e30f; l_run[r] = 0.0f; }
  const int kvend = qt * 64 + 64;

  for (int kv0 = 0; kv0 < kvend; kv0 += 32) {
    {
      int kvi = tid >> 3, c8 = (tid & 7) * 8;
      *reinterpret_cast<short8*>(&Ks[kvi][c8]) =
          *reinterpret_cast<const short8*>(kmat + (size_t)(kv0 + kvi) * DMODEL + h * DHEAD + c8);
      short8 vv = *reinterpret_cast<const short8*>(v + (size_t)(kv0 + kvi) * DMODEL + h * DHEAD + c8);
#pragma unroll
      for (int j = 0; j < 8; ++j) Vt[c8 + j][kvi] = (u16)vv[j];
    }
    __syncthreads();

    float sm[2][4];
#pragma unroll
    for (int t2 = 0; t2 < 2; ++t2) {
      short8 bk0 = *reinterpret_cast<const short8*>(&Ks[t2 * 16 + (lane & 15)][(lane >> 4) * 8]);
      short8 bk1 = *reinterpret_cast<const short8*>(&Ks[t2 * 16 + (lane & 15)][32 + (lane >> 4) * 8]);
      f32x4 s4 = {};
      s4 = mfma16(aq0, bk0, s4);
      s4 = mfma16(aq1, bk1, s4);
#pragma unroll
      for (int r = 0; r < 4; ++r) {
        int rowg = qw0 + (lane >> 4) * 4 + r;
        int colg = kv0 + t2 * 16 + (lane & 15);
        float val = s4[r] * 0.03125f;
        sm[t2][r] = (colg <= rowg) ? val : -1e30f;
      }
    }
    float alpha[4], p0[4], p1[4];
#pragma unroll
    for (int r = 0; r < 4; ++r) {
      float mx = fmaxf(sm[0][r], sm[1][r]);
#pragma unroll
      for (int d = 1; d < 16; d <<= 1) mx = fmaxf(mx, __shfl_xor(mx, d));
      float mn = fmaxf(m_run[r], mx);
      alpha[r] = __expf(m_run[r] - mn);
      p0[r] = __expf(sm[0][r] - mn);
      p1[r] = __expf(sm[1][r] - mn);
      float ps = p0[r] + p1[r];
#pragma unroll
      for (int d = 1; d < 16; d <<= 1) ps += __shfl_xor(ps, d);
      l_run[r] = l_run[r] * alpha[r] + ps;
      m_run[r] = mn;
    }
#pragma unroll
    for (int fn = 0; fn < 4; ++fn) {
      f32x4 t = oacc[fn];
      t[0] *= alpha[0]; t[1] *= alpha[1]; t[2] *= alpha[2]; t[3] *= alpha[3];
      oacc[fn] = t;
    }
#pragma unroll
    for (int r = 0; r < 4; ++r) {
      int rit = (lane >> 4) * 4 + r;
      Pl[wid][rit][lane & 15]        = f2b(p0[r]);
      Pl[wid][rit][16 + (lane & 15)] = f2b(p1[r]);
    }
    short8 pa = *reinterpret_cast<const short8*>(&Pl[wid][lane & 15][(lane >> 4) * 8]);
#pragma unroll
    for (int fn = 0; fn < 4; ++fn) {
      short8 bv = *reinterpret_cast<const short8*>(&Vt[fn * 16 + (lane & 15)][(lane >> 4) * 8]);
      oacc[fn] = mfma16(pa, bv, oacc[fn]);
    }
    __syncthreads();
  }
#pragma unroll
  for (int fn = 0; fn < 4; ++fn) {
#pragma unroll
    for (int r = 0; r < 4; ++r) {
      int row = qw0 + (lane >> 4) * 4 + r;
      float val = oacc[fn][r] / l_run[r];
      o[(size_t)row * DMODEL + h * DHEAD + fn * 16 + (lane & 15)] = f2b(val);
    }
  }
}

// ---------------- launch ----------------
extern "C" void kernel_launch(void* const* d_in, const int* in_sizes, int n_in,
                              void* d_out, int out_size, void* d_ws, size_t ws_size,
                              hipStream_t stream) {
  (void)in_sizes; (void)n_in; (void)out_size;
  const int*   tok    = (const int*)d_in[0];
  const float* emb    = (const float*)d_in[1];
  const float* finalb = (const float*)d_in[2];
  const float* Wq     = (const float*)d_in[3];
  const float* Wk     = (const float*)d_in[4];
  const float* Wv     = (const float*)d_in[5];
  const float* Wo     = (const float*)d_in[6];
  const float* ln1s   = (const float*)d_in[7];
  const float* ln1b   = (const float*)d_in[8];
  const float* W1     = (const float*)d_in[9];
  const float* b1     = (const float*)d_in[10];
  const float* W2     = (const float*)d_in[11];
  const float* b2     = (const float*)d_in[12];
  const float* ln2s   = (const float*)d_in[13];
  const float* ln2b   = (const float*)d_in[14];
  float* out = (float*)d_out;

  // workspace layout
  float* x   = (float*)d_ws;                       // 4 MB
  float* y   = x + LSEQ * DMODEL;                  // 4 MB
  u16* xb    = (u16*)(y + LSEQ * DMODEL);          // 2 MB
  u16* qb    = xb + LSEQ * DMODEL;
  u16* kb    = qb + LSEQ * DMODEL;
  u16* vb    = kb + LSEQ * DMODEL;
  u16* ob    = vb + LSEQ * DMODEL;
  u16* h1    = ob + LSEQ * DMODEL;                 // 8 MB
  u16* qkvT  = h1 + LSEQ * DFF;                    // [3072][1024] 6 MB
  u16* woT   = qkvT + 3 * DMODEL * DMODEL;         // [1024][1024] 2 MB
  u16* w1T   = woT + DMODEL * DMODEL;              // [4096][1024] 8 MB
  u16* w2T   = w1T + DFF * DMODEL;                 // [1024][4096] 8 MB
  u16* embT  = w2T + DMODEL * DFF;                 // [32000][1024] 65.5 MB
  const size_t need_embT = ((size_t)(embT - (u16*)d_ws)) * 2 + (size_t)NVOCAB * DMODEL * 2;
  const bool big_ws = ws_size >= need_embT;

  embed_k<<<LSEQ, 256, 0, stream>>>(tok, emb, x, xb);

  for (int l = 0; l < NLAYER; ++l) {
    const float* wq  = Wq + (size_t)l * NHEAD * DMODEL * DHEAD;
    const float* wk  = Wk + (size_t)l * NHEAD * DMODEL * DHEAD;
    const float* wv  = Wv + (size_t)l * NHEAD * DMODEL * DHEAD;
    const float* wo  = Wo + (size_t)l * DMODEL * DMODEL;
    const float* w1  = W1 + (size_t)l * DMODEL * DFF;
    const float* b1l = b1 + (size_t)l * DFF;
    const float* w2  = W2 + (size_t)l * DFF * DMODEL;
    const float* b2l = b2 + (size_t)l * DMODEL;

    // weight conversion (bf16 B^T): per-head transposes for q/k/v, full for wo/w1/w2
    tconv_k<<<dim3(1, 16, 16), 256, 0, stream>>>(wq, qkvT, DMODEL, DHEAD, 0,    DMODEL * DHEAD);
    tconv_k<<<dim3(1, 16, 16), 256, 0, stream>>>(wk, qkvT, DMODEL, DHEAD, 1024, DMODEL * DHEAD);
    tconv_k<<<dim3(1, 16, 16), 256, 0, stream>>>(wv, qkvT, DMODEL, DHEAD, 2048, DMODEL * DHEAD);
    tconv_k<<<dim3(16, 16, 1), 256, 0, stream>>>(wo, woT, DMODEL, DMODEL, 0, 0);
    tconv_k<<<dim3(64, 16, 1), 256, 0, stream>>>(w1, w1T, DMODEL, DFF, 0, 0);
    tconv_k<<<dim3(16, 64, 1), 256, 0, stream>>>(w2, w2T, DFF, DMODEL, 0, 0);

    // fused QKV: [1024,1024] x [1024,3072]
    gemm_bt<64, 128, 0, false, false, 2><<<dim3(24, 16), 256, 0, stream>>>(
        xb, DMODEL, qkvT, DMODEL, nullptr, qb, DMODEL, DMODEL);
    attn_k<<<dim3(16, 16), 256, 0, stream>>>(qb, kb, vb, ob);
    gemm_bt<64, 64, 0, false, false, 0><<<dim3(16, 16), 256, 0, stream>>>(
        ob, DMODEL, woT, DMODEL, nullptr, y, DMODEL, DMODEL);
    ln_k<<<LSEQ, 256, 0, stream>>>(x, y, ln1s + (size_t)l * DMODEL, ln1b + (size_t)l * DMODEL, x, xb);
    gemm_bt<64, 128, 0, true, true, 1><<<dim3(32, 16), 256, 0, stream>>>(
        xb, DMODEL, w1T, DMODEL, b1l, h1, DFF, DMODEL);
    gemm_bt<64, 64, 0, true, false, 0><<<dim3(16, 16), 256, 0, stream>>>(
        h1, DFF, w2T, DFF, b2l, y, DMODEL, DFF);
    ln_k<<<LSEQ, 256, 0, stream>>>(x, y, ln2s + (size_t)l * DMODEL, ln2b + (size_t)l * DMODEL, x, xb);
  }

  // logits = x @ emb^T + final_b
  if (big_ws) {
    ec_k<<<(NVOCAB * DMODEL) / 2048, 256, 0, stream>>>(emb, embT);
    gemm_bt<128, 128, 0, true, false, 0><<<dim3(250, 8), 256, 0, stream>>>(
        xb, DMODEL, embT, DMODEL, finalb, out, NVOCAB, DMODEL);
  } else {
    gemm_bt<128, 128, 1, true, false, 0><<<dim3(250, 8), 256, 0, stream>>>(
        xb, DMODEL, emb, DMODEL, finalb, out, NVOCAB, DMODEL);
  }
}

// Round 3
// 2198.808 us; speedup vs baseline: 1.7269x; 1.0819x over previous
//
#include <hip/hip_runtime.h>

typedef unsigned short u16;
typedef __attribute__((ext_vector_type(8))) short short8;
typedef __attribute__((ext_vector_type(4))) float f32x4;
typedef __attribute__((ext_vector_type(4))) u16 u16x4;

#define LSEQ   1024
#define DMODEL 1024
#define NHEAD  16
#define DHEAD  64
#define DFF    4096
#define NLAYER 12
#define NVOCAB 32000

__device__ __forceinline__ u16 f2b(float f) {
  union { float f; unsigned u; } x; x.f = f;
  unsigned r = x.u + 0x7fffu + ((x.u >> 16) & 1u);   // RNE
  return (u16)(r >> 16);
}

__device__ __forceinline__ f32x4 mfma16(short8 a, short8 b, f32x4 c) {
  return __builtin_amdgcn_mfma_f32_16x16x32_bf16(a, b, c, 0, 0, 0);
}

// async global->LDS, 16B per lane. LDS dest = wave-uniform base + lane*16.
__device__ __forceinline__ void gload16(const u16* g, u16* l) {
  __builtin_amdgcn_global_load_lds(
      (const __attribute__((address_space(1))) void*)g,
      (__attribute__((address_space(3))) void*)l, 16, 0, 0);
}

// ---------------- embedding + positional encoding ----------------
__global__ __launch_bounds__(256) void embed_k(const int* __restrict__ tok,
    const float* __restrict__ emb, float* __restrict__ x, u16* __restrict__ xb)
{
  const int l = blockIdx.x;
  const int d0 = threadIdx.x * 4;
  const int t = tok[l];
  const float lf = (float)l;
  float o[4]; u16 obv[4];
#pragma unroll
  for (int j = 0; j < 4; ++j) {
    int d = d0 + j;
    int p = d >> 1;
    float ang = lf * powf(10000.0f, -(float)(2 * p) / 1024.0f);
    float pe = (d & 1) ? cosf(ang) : sinf(ang);
    float val = 2.0f * emb[(size_t)t * DMODEL + d] * 55.42562584220407f + pe; // sqrt(3072)
    o[j] = val; obv[j] = f2b(val);
  }
  *reinterpret_cast<float4*>(x + (size_t)l * DMODEL + d0) = make_float4(o[0], o[1], o[2], o[3]);
  u16x4 vb = { obv[0], obv[1], obv[2], obv[3] };
  *reinterpret_cast<u16x4*>(xb + (size_t)l * DMODEL + d0) = vb;
}

// ---------------- residual-add + LayerNorm ----------------
__global__ __launch_bounds__(256) void ln_k(const float* __restrict__ xin,
    const float* __restrict__ yin, const float* __restrict__ s, const float* __restrict__ b,
    float* __restrict__ xout, u16* __restrict__ xbout)
{
  const int row = blockIdx.x, tid = threadIdx.x;
  const int d0 = tid * 4;
  float4 xv = *reinterpret_cast<const float4*>(xin + (size_t)row * DMODEL + d0);
  float4 yv = *reinterpret_cast<const float4*>(yin + (size_t)row * DMODEL + d0);
  float t0 = xv.x + yv.x, t1 = xv.y + yv.y, t2 = xv.z + yv.z, t3 = xv.w + yv.w;
  float sum = t0 + t1 + t2 + t3;
  float sq  = t0 * t0 + t1 * t1 + t2 * t2 + t3 * t3;
#pragma unroll
  for (int d = 1; d < 64; d <<= 1) { sum += __shfl_xor(sum, d); sq += __shfl_xor(sq, d); }
  __shared__ float ssum[4], ssq[4];
  const int wid = tid >> 6;
  if ((tid & 63) == 0) { ssum[wid] = sum; ssq[wid] = sq; }
  __syncthreads();
  sum = ssum[0] + ssum[1] + ssum[2] + ssum[3];
  sq  = ssq[0] + ssq[1] + ssq[2] + ssq[3];
  const float mu = sum * (1.0f / 1024.0f);
  const float var = sq * (1.0f / 1024.0f) - mu * mu;
  const float rstd = rsqrtf(var + 1e-5f);
  float4 sv = *reinterpret_cast<const float4*>(s + d0);
  float4 bv = *reinterpret_cast<const float4*>(b + d0);
  float o0 = (t0 - mu) * rstd * sv.x + bv.x;
  float o1 = (t1 - mu) * rstd * sv.y + bv.y;
  float o2 = (t2 - mu) * rstd * sv.z + bv.z;
  float o3 = (t3 - mu) * rstd * sv.w + bv.w;
  *reinterpret_cast<float4*>(xout + (size_t)row * DMODEL + d0) = make_float4(o0, o1, o2, o3);
  u16x4 vb = { f2b(o0), f2b(o1), f2b(o2), f2b(o3) };
  *reinterpret_cast<u16x4*>(xbout + (size_t)row * DMODEL + d0) = vb;
}

// ---------------- transpose-convert: f32 in[R][C] -> bf16 out rows ----------------
// out row for (z, c): (z/zper)*lstride + (z%zper)*C + obase + c ; out row length R
__global__ __launch_bounds__(256) void tconv_k(const float* __restrict__ in, u16* __restrict__ out,
                                               int R, int C, int zper, int lstride, int obase, int zstride)
{
  __shared__ float t[64][65];
  const int rt = blockIdx.y * 64, ct = blockIdx.x * 64;
  const int z = blockIdx.z;
  in += (size_t)z * zstride;
  const int tr = threadIdx.x >> 4, tc = threadIdx.x & 15;
#pragma unroll
  for (int i = 0; i < 4; ++i) {
    int r = i * 16 + tr;
    float4 v = *reinterpret_cast<const float4*>(in + (size_t)(rt + r) * C + ct + tc * 4);
    t[r][tc * 4 + 0] = v.x; t[r][tc * 4 + 1] = v.y;
    t[r][tc * 4 + 2] = v.z; t[r][tc * 4 + 3] = v.w;
  }
  __syncthreads();
  const size_t orow0 = (size_t)(z / zper) * lstride + (size_t)(z % zper) * C + obase + ct;
#pragma unroll
  for (int i = 0; i < 4; ++i) {
    int c = i * 16 + tr;
    u16x4 o;
    o[0] = f2b(t[tc * 4 + 0][c]); o[1] = f2b(t[tc * 4 + 1][c]);
    o[2] = f2b(t[tc * 4 + 2][c]); o[3] = f2b(t[tc * 4 + 3][c]);
    *reinterpret_cast<u16x4*>(out + (orow0 + c) * R + rt + tc * 4) = o;
  }
}

// ---------------- elementwise convert f32 -> bf16 ----------------
__global__ __launch_bounds__(256) void ec_k(const float* __restrict__ in, u16* __restrict__ out)
{
  const size_t i = ((size_t)blockIdx.x * 256 + threadIdx.x) * 8;
  float4 a = *reinterpret_cast<const float4*>(in + i);
  float4 b = *reinterpret_cast<const float4*>(in + i + 4);
  short8 o;
  o[0] = f2b(a.x); o[1] = f2b(a.y); o[2] = f2b(a.z); o[3] = f2b(a.w);
  o[4] = f2b(b.x); o[5] = f2b(b.y); o[6] = f2b(b.z); o[7] = f2b(b.w);
  *reinterpret_cast<short8*>(out + i) = o;
}

// ---------------- bf16 MFMA GEMM ----------------
// C[M,N] = act(A[M,K] * Bt[N,K]^T + bias); grid: x = M tiles (fastest), y = N tiles.
// BK=64 path uses T2 XOR swizzle (pre-swizzled global source + swizzled ds_read).
// BSRC: 0 = bf16 B^T via global_load_lds; 1 = f32 B^T reg-staged (BK must be 32, BN 128)
// OUTMODE: 0 = f32; 1 = bf16; 2 = QKV triple bf16 [L,1024] x3
template<int BM, int BN, int BK, int BSRC, bool BIAS, bool RELU, int OUTMODE>
__global__ __launch_bounds__(256) void gemm_bt(
    const u16* __restrict__ A, int lda,
    const void* __restrict__ Bp, int ldb,
    const float* __restrict__ bias,
    void* __restrict__ Cv, int ldc, int Ktot)
{
  __shared__ u16 As[BM * BK];
  __shared__ u16 Bs[BN * BK];
  const int tid = threadIdx.x, lane = tid & 63, wid = tid >> 6;
  // chunked XCD swizzle (bijective: all grids are multiples of 8)
  const int nwg = gridDim.x * gridDim.y;
  const int flat = blockIdx.y * gridDim.x + blockIdx.x;
  const int qq = nwg >> 3;
  const int ni = (flat & 7) * qq + (flat >> 3);
  const int m0 = (ni % gridDim.x) * BM, n0 = (ni / gridDim.x) * BN;
  constexpr int FM = BM / 32, FN = BN / 32;
  constexpr int KS = BK / 32;
  constexpr int CPR = BK / 8;     // 16B chunks per row
  const int wm = (wid >> 1) * (BM / 2), wn = (wid & 1) * (BN / 2);
  const u16* Bt = (const u16*)Bp;
  const float* Bf = (const float*)Bp;
  f32x4 acc[FM][FN] = {};

  for (int k0 = 0; k0 < Ktot; k0 += BK) {
    // ---- stage A via global_load_lds ----
#pragma unroll
    for (int i = 0; i < (BM * CPR) / 256; ++i) {
      int c = i * 256 + wid * 64 + lane;
      int row = c / CPR, p0 = c % CPR;
      int part = (BK == 64) ? (p0 ^ (row & 7)) : p0;
      gload16(A + (size_t)(m0 + row) * lda + k0 + part * 8,
              &As[(i * 256 + wid * 64) * 8]);
    }
    // ---- stage B ----
    if constexpr (BSRC == 0) {
#pragma unroll
      for (int i = 0; i < (BN * CPR) / 256; ++i) {
        int c = i * 256 + wid * 64 + lane;
        int row = c / CPR, p0 = c % CPR;
        int part = (BK == 64) ? (p0 ^ (row & 7)) : p0;
        gload16(Bt + (size_t)(n0 + row) * ldb + k0 + part * 8,
                &Bs[(i * 256 + wid * 64) * 8]);
      }
    } else {                       // f32 B^T, reg-stage + convert (BK=32, BN=128)
      int row = tid >> 1, kh = (tid & 1) * 16;
      const float* src = Bf + (size_t)(n0 + row) * ldb + k0 + kh;
      float4 v0 = *reinterpret_cast<const float4*>(src);
      float4 v1 = *reinterpret_cast<const float4*>(src + 4);
      float4 v2 = *reinterpret_cast<const float4*>(src + 8);
      float4 v3 = *reinterpret_cast<const float4*>(src + 12);
      short8 p0, p1;
      p0[0] = f2b(v0.x); p0[1] = f2b(v0.y); p0[2] = f2b(v0.z); p0[3] = f2b(v0.w);
      p0[4] = f2b(v1.x); p0[5] = f2b(v1.y); p0[6] = f2b(v1.z); p0[7] = f2b(v1.w);
      p1[0] = f2b(v2.x); p1[1] = f2b(v2.y); p1[2] = f2b(v2.z); p1[3] = f2b(v2.w);
      p1[4] = f2b(v3.x); p1[5] = f2b(v3.y); p1[6] = f2b(v3.z); p1[7] = f2b(v3.w);
      *reinterpret_cast<short8*>(&Bs[row * BK + kh])     = p0;
      *reinterpret_cast<short8*>(&Bs[row * BK + kh + 8]) = p1;
    }
    __syncthreads();
    short8 a[KS][FM], b[KS][FN];
#pragma unroll
    for (int ks = 0; ks < KS; ++ks) {
#pragma unroll
      for (int fm = 0; fm < FM; ++fm) {
        int row = wm + fm * 16 + (lane & 15);
        int pidx = ks * 4 + (lane >> 4);
        if (BK == 64) pidx ^= (row & 7);
        a[ks][fm] = *reinterpret_cast<const short8*>(&As[row * BK + pidx * 8]);
      }
#pragma unroll
      for (int fn = 0; fn < FN; ++fn) {
        int row = wn + fn * 16 + (lane & 15);
        int pidx = ks * 4 + (lane >> 4);
        if (BK == 64) pidx ^= (row & 7);
        b[ks][fn] = *reinterpret_cast<const short8*>(&Bs[row * BK + pidx * 8]);
      }
    }
#pragma unroll
    for (int ks = 0; ks < KS; ++ks)
#pragma unroll
      for (int fm = 0; fm < FM; ++fm)
#pragma unroll
        for (int fn = 0; fn < FN; ++fn)
          acc[fm][fn] = mfma16(a[ks][fm], b[ks][fn], acc[fm][fn]);
    __syncthreads();
  }

  // ---- epilogue ----
#pragma unroll
  for (int fm = 0; fm < FM; ++fm) {
#pragma unroll
    for (int fn = 0; fn < FN; ++fn) {
#pragma unroll
      for (int r = 0; r < 4; ++r) {
        int row = m0 + wm + fm * 16 + (lane >> 4) * 4 + r;
        int col = n0 + wn + fn * 16 + (lane & 15);
        float val = acc[fm][fn][r];
        if (BIAS) val += bias[col];
        if (RELU) val = fmaxf(val, 0.0f);
        if (OUTMODE == 0) {
          ((float*)Cv)[(size_t)row * ldc + col] = val;
        } else if (OUTMODE == 1) {
          ((u16*)Cv)[(size_t)row * ldc + col] = f2b(val);
        } else {
          int sel = col >> 10, cc = col & 1023;
          ((u16*)Cv)[(size_t)sel * (LSEQ * DMODEL) + (size_t)row * DMODEL + cc] = f2b(val);
        }
      }
    }
  }
}

// ---------------- causal flash attention, KVBLK=64 ----------------
__global__ __launch_bounds__(256) void attn_k(const u16* __restrict__ q,
    const u16* __restrict__ kmat, const u16* __restrict__ v, u16* __restrict__ o)
{
  __shared__ u16 Ks[64][72];
  __shared__ u16 Vt[64][72];
  __shared__ u16 Pl[4][16][72];
  const int tid = threadIdx.x, lane = tid & 63, wid = tid >> 6;
  const int h = blockIdx.y, qt = blockIdx.x;
  const int qw0 = qt * 64 + wid * 16;
  const int qrow = qw0 + (lane & 15);
  const short8 aq0 = *reinterpret_cast<const short8*>(q + (size_t)qrow * DMODEL + h * DHEAD + (lane >> 4) * 8);
  const short8 aq1 = *reinterpret_cast<const short8*>(q + (size_t)qrow * DMODEL + h * DHEAD + 32 + (lane >> 4) * 8);
  float m_run[4], l_run[4];
  f32x4 oacc[4] = {};
#pragma unroll
  for (int r = 0; r < 4; ++r) { m_run[r] = -1e30f; l_run[r] = 0.0f; }
  const int kvend = qt * 64 + 64;

  for (int kv0 = 0; kv0 < kvend; kv0 += 64) {
    { // stage K [64,64] as-is, V [64,64] transposed
      int kvi = tid >> 2, c16 = (tid & 3) * 16;
      const u16* kp = kmat + (size_t)(kv0 + kvi) * DMODEL + h * DHEAD + c16;
      *reinterpret_cast<short8*>(&Ks[kvi][c16])     = *reinterpret_cast<const short8*>(kp);
      *reinterpret_cast<short8*>(&Ks[kvi][c16 + 8]) = *reinterpret_cast<const short8*>(kp + 8);
      const u16* vp = v + (size_t)(kv0 + kvi) * DMODEL + h * DHEAD + c16;
      short8 v0 = *reinterpret_cast<const short8*>(vp);
      short8 v1 = *reinterpret_cast<const short8*>(vp + 8);
#pragma unroll
      for (int j = 0; j < 8; ++j) { Vt[c16 + j][kvi] = (u16)v0[j]; Vt[c16 + 8 + j][kvi] = (u16)v1[j]; }
    }
    __syncthreads();

    float sm[4][4];
#pragma unroll
    for (int t2 = 0; t2 < 4; ++t2) {
      short8 bk0 = *reinterpret_cast<const short8*>(&Ks[t2 * 16 + (lane & 15)][(lane >> 4) * 8]);
      short8 bk1 = *reinterpret_cast<const short8*>(&Ks[t2 * 16 + (lane & 15)][32 + (lane >> 4) * 8]);
      f32x4 s4 = {};
      s4 = mfma16(aq0, bk0, s4);
      s4 = mfma16(aq1, bk1, s4);
#pragma unroll
      for (int r = 0; r < 4; ++r) {
        int rowg = qw0 + (lane >> 4) * 4 + r;
        int colg = kv0 + t2 * 16 + (lane & 15);
        float val = s4[r] * 0.03125f;                 // 1/sqrt(d_model)=1/32
        sm[t2][r] = (colg <= rowg) ? val : -1e30f;
      }
    }
    float alpha[4], p[4][4];
#pragma unroll
    for (int r = 0; r < 4; ++r) {
      float mx = fmaxf(fmaxf(sm[0][r], sm[1][r]), fmaxf(sm[2][r], sm[3][r]));
#pragma unroll
      for (int d = 1; d < 16; d <<= 1) mx = fmaxf(mx, __shfl_xor(mx, d));
      float mn = fmaxf(m_run[r], mx);
      alpha[r] = __expf(m_run[r] - mn);
      float ps = 0.0f;
#pragma unroll
      for (int t2 = 0; t2 < 4; ++t2) { p[t2][r] = __expf(sm[t2][r] - mn); ps += p[t2][r]; }
#pragma unroll
      for (int d = 1; d < 16; d <<= 1) ps += __shfl_xor(ps, d);
      l_run[r] = l_run[r] * alpha[r] + ps;
      m_run[r] = mn;
    }
#pragma unroll
    for (int fn = 0; fn < 4; ++fn) {
      f32x4 t = oacc[fn];
      t[0] *= alpha[0]; t[1] *= alpha[1]; t[2] *= alpha[2]; t[3] *= alpha[3];
      oacc[fn] = t;
    }
#pragma unroll
    for (int r = 0; r < 4; ++r) {
      int rit = (lane >> 4) * 4 + r;
#pragma unroll
      for (int t2 = 0; t2 < 4; ++t2)
        Pl[wid][rit][t2 * 16 + (lane & 15)] = f2b(p[t2][r]);
    }
    short8 pa0 = *reinterpret_cast<const short8*>(&Pl[wid][lane & 15][(lane >> 4) * 8]);
    short8 pa1 = *reinterpret_cast<const short8*>(&Pl[wid][lane & 15][32 + (lane >> 4) * 8]);
#pragma unroll
    for (int fn = 0; fn < 4; ++fn) {
      short8 bv0 = *reinterpret_cast<const short8*>(&Vt[fn * 16 + (lane & 15)][(lane >> 4) * 8]);
      short8 bv1 = *reinterpret_cast<const short8*>(&Vt[fn * 16 + (lane & 15)][32 + (lane >> 4) * 8]);
      oacc[fn] = mfma16(pa0, bv0, oacc[fn]);
      oacc[fn] = mfma16(pa1, bv1, oacc[fn]);
    }
    __syncthreads();
  }
#pragma unroll
  for (int fn = 0; fn < 4; ++fn) {
#pragma unroll
    for (int r = 0; r < 4; ++r) {
      int row = qw0 + (lane >> 4) * 4 + r;
      float val = oacc[fn][r] / l_run[r];
      o[(size_t)row * DMODEL + h * DHEAD + fn * 16 + (lane & 15)] = f2b(val);
    }
  }
}

// ---------------- launch ----------------
extern "C" void kernel_launch(void* const* d_in, const int* in_sizes, int n_in,
                              void* d_out, int out_size, void* d_ws, size_t ws_size,
                              hipStream_t stream) {
  (void)in_sizes; (void)n_in; (void)out_size;
  const int*   tok    = (const int*)d_in[0];
  const float* emb    = (const float*)d_in[1];
  const float* finalb = (const float*)d_in[2];
  const float* Wq     = (const float*)d_in[3];
  const float* Wk     = (const float*)d_in[4];
  const float* Wv     = (const float*)d_in[5];
  const float* Wo     = (const float*)d_in[6];
  const float* ln1s   = (const float*)d_in[7];
  const float* ln1b   = (const float*)d_in[8];
  const float* W1     = (const float*)d_in[9];
  const float* b1     = (const float*)d_in[10];
  const float* W2     = (const float*)d_in[11];
  const float* b2     = (const float*)d_in[12];
  const float* ln2s   = (const float*)d_in[13];
  const float* ln2b   = (const float*)d_in[14];
  float* out = (float*)d_out;

  // workspace: activations
  float* x   = (float*)d_ws;                       // 4 MiB
  float* y   = x + LSEQ * DMODEL;                  // 4 MiB
  u16* xb    = (u16*)(y + LSEQ * DMODEL);
  u16* qb    = xb + LSEQ * DMODEL;
  u16* kb    = qb + LSEQ * DMODEL;
  u16* vb    = kb + LSEQ * DMODEL;
  u16* ob    = vb + LSEQ * DMODEL;
  u16* h1    = ob + LSEQ * DMODEL;                 // 8 MiB
  u16* wbase = h1 + LSEQ * DFF;

  const size_t eQKV = (size_t)3 * DMODEL * DMODEL;   // 3M u16 / layer
  const size_t eWO  = (size_t)DMODEL * DMODEL;
  const size_t eW1  = (size_t)DFF * DMODEL;
  const size_t eW2  = (size_t)DMODEL * DFF;
  const size_t perL = eQKV + eWO + eW1 + eW2;        // 12M u16 / layer
  const size_t eEMB = (size_t)NVOCAB * DMODEL;
  const size_t actE = (size_t)(wbase - (u16*)d_ws);
  const size_t bigNeed = (actE + NLAYER * perL + eEMB) * 2;
  const size_t midNeed = (actE + perL + eEMB) * 2;
  const int mode = ws_size >= bigNeed ? 2 : (ws_size >= midNeed ? 1 : 0);
  const int WL = (mode == 2) ? NLAYER : 1;           // stored layers of weights

  u16* qkvT = wbase;
  u16* woT  = qkvT + WL * eQKV;
  u16* w1T  = woT  + WL * eWO;
  u16* w2T  = w1T  + WL * eW1;
  u16* embT = w2T  + WL * eW2;

  if (mode == 2) {
    // batched upfront conversion: q/k/v over z = layer*16+head; wo/w1/w2 over z = layer
    tconv_k<<<dim3(1, 16, 192), 256, 0, stream>>>(Wq, qkvT, DMODEL, DHEAD, 16, 3 * DMODEL, 0,    DMODEL * DHEAD);
    tconv_k<<<dim3(1, 16, 192), 256, 0, stream>>>(Wk, qkvT, DMODEL, DHEAD, 16, 3 * DMODEL, 1024, DMODEL * DHEAD);
    tconv_k<<<dim3(1, 16, 192), 256, 0, stream>>>(Wv, qkvT, DMODEL, DHEAD, 16, 3 * DMODEL, 2048, DMODEL * DHEAD);
    tconv_k<<<dim3(16, 16, 12), 256, 0, stream>>>(Wo, woT, DMODEL, DMODEL, 1, DMODEL, 0, DMODEL * DMODEL);
    tconv_k<<<dim3(64, 16, 12), 256, 0, stream>>>(W1, w1T, DMODEL, DFF, 1, DFF, 0, DMODEL * DFF);
    tconv_k<<<dim3(16, 64, 12), 256, 0, stream>>>(W2, w2T, DFF, DMODEL, 1, DMODEL, 0, DFF * DMODEL);
    ec_k<<<(NVOCAB * DMODEL) / 2048, 256, 0, stream>>>(emb, embT);
  } else if (mode == 1) {
    ec_k<<<(NVOCAB * DMODEL) / 2048, 256, 0, stream>>>(emb, embT);
  }

  embed_k<<<LSEQ, 256, 0, stream>>>(tok, emb, x, xb);

  for (int l = 0; l < NLAYER; ++l) {
    const float* wq  = Wq + (size_t)l * NHEAD * DMODEL * DHEAD;
    const float* wk  = Wk + (size_t)l * NHEAD * DMODEL * DHEAD;
    const float* wv  = Wv + (size_t)l * NHEAD * DMODEL * DHEAD;
    const float* wo  = Wo + (size_t)l * DMODEL * DMODEL;
    const float* w1  = W1 + (size_t)l * DMODEL * DFF;
    const float* b1l = b1 + (size_t)l * DFF;
    const float* w2  = W2 + (size_t)l * DFF * DMODEL;
    const float* b2l = b2 + (size_t)l * DMODEL;
    u16* qkvTl = qkvT + (mode == 2 ? (size_t)l * eQKV : 0);
    u16* woTl  = woT  + (mode == 2 ? (size_t)l * eWO  : 0);
    u16* w1Tl  = w1T  + (mode == 2 ? (size_t)l * eW1  : 0);
    u16* w2Tl  = w2T  + (mode == 2 ? (size_t)l * eW2  : 0);

    if (mode < 2) {   // per-layer conversion
      tconv_k<<<dim3(1, 16, 16), 256, 0, stream>>>(wq, qkvTl, DMODEL, DHEAD, 16, 0, 0,    DMODEL * DHEAD);
      tconv_k<<<dim3(1, 16, 16), 256, 0, stream>>>(wk, qkvTl, DMODEL, DHEAD, 16, 0, 1024, DMODEL * DHEAD);
      tconv_k<<<dim3(1, 16, 16), 256, 0, stream>>>(wv, qkvTl, DMODEL, DHEAD, 16, 0, 2048, DMODEL * DHEAD);
      tconv_k<<<dim3(16, 16, 1), 256, 0, stream>>>(wo, woTl, DMODEL, DMODEL, 1, 0, 0, 0);
      tconv_k<<<dim3(64, 16, 1), 256, 0, stream>>>(w1, w1Tl, DMODEL, DFF, 1, 0, 0, 0);
      tconv_k<<<dim3(16, 64, 1), 256, 0, stream>>>(w2, w2Tl, DFF, DMODEL, 1, 0, 0, 0);
    }

    // fused QKV: [1024,1024] x [1024,3072] -> q,k,v bf16
    gemm_bt<64, 128, 64, 0, false, false, 2><<<dim3(16, 24), 256, 0, stream>>>(
        xb, DMODEL, qkvTl, DMODEL, nullptr, qb, DMODEL, DMODEL);
    attn_k<<<dim3(16, 16), 256, 0, stream>>>(qb, kb, vb, ob);
    gemm_bt<64, 64, 64, 0, false, false, 0><<<dim3(16, 16), 256, 0, stream>>>(
        ob, DMODEL, woTl, DMODEL, nullptr, y, DMODEL, DMODEL);
    ln_k<<<LSEQ, 256, 0, stream>>>(x, y, ln1s + (size_t)l * DMODEL, ln1b + (size_t)l * DMODEL, x, xb);
    gemm_bt<64, 128, 64, 0, true, true, 1><<<dim3(16, 32), 256, 0, stream>>>(
        xb, DMODEL, w1Tl, DMODEL, b1l, h1, DFF, DMODEL);
    gemm_bt<64, 64, 64, 0, true, false, 0><<<dim3(16, 16), 256, 0, stream>>>(
        h1, DFF, w2Tl, DFF, b2l, y, DMODEL, DFF);
    ln_k<<<LSEQ, 256, 0, stream>>>(x, y, ln2s + (size_t)l * DMODEL, ln2b + (size_t)l * DMODEL, x, xb);
  }

  // logits = x @ emb^T + final_b
  if (mode >= 1) {
    gemm_bt<128, 128, 32, 0, true, false, 0><<<dim3(8, 250), 256, 0, stream>>>(
        xb, DMODEL, embT, DMODEL, finalb, out, NVOCAB, DMODEL);
  } else {
    gemm_bt<128, 128, 32, 1, true, false, 0><<<dim3(8, 250), 256, 0, stream>>>(
        xb, DMODEL, emb, DMODEL, finalb, out, NVOCAB, DMODEL);
  }
}

// Round 4
// 2113.722 us; speedup vs baseline: 1.7964x; 1.0403x over previous
//
#include <hip/hip_runtime.h>

typedef unsigned short u16;
typedef __attribute__((ext_vector_type(8))) short short8;
typedef __attribute__((ext_vector_type(4))) float f32x4;
typedef __attribute__((ext_vector_type(4))) u16 u16x4;

#define LSEQ   1024
#define DMODEL 1024
#define NHEAD  16
#define DHEAD  64
#define DFF    4096
#define NLAYER 12
#define NVOCAB 32000

__device__ __forceinline__ u16 f2b(float f) {
  union { float f; unsigned u; } x; x.f = f;
  unsigned r = x.u + 0x7fffu + ((x.u >> 16) & 1u);   // RNE
  return (u16)(r >> 16);
}

__device__ __forceinline__ f32x4 mfma16(short8 a, short8 b, f32x4 c) {
  return __builtin_amdgcn_mfma_f32_16x16x32_bf16(a, b, c, 0, 0, 0);
}

// async global->LDS, 16B per lane. LDS dest = wave-uniform base + lane*16.
__device__ __forceinline__ void gload16(const u16* g, u16* l) {
  __builtin_amdgcn_global_load_lds(
      (const __attribute__((address_space(1))) void*)g,
      (__attribute__((address_space(3))) void*)l, 16, 0, 0);
}

// ---------------- embedding + positional encoding ----------------
__global__ __launch_bounds__(256) void embed_k(const int* __restrict__ tok,
    const float* __restrict__ emb, float* __restrict__ x, u16* __restrict__ xb)
{
  const int l = blockIdx.x;
  const int d0 = threadIdx.x * 4;
  const int t = tok[l];
  const float lf = (float)l;
  float o[4]; u16 obv[4];
#pragma unroll
  for (int j = 0; j < 4; ++j) {
    int d = d0 + j;
    int p = d >> 1;
    float ang = lf * powf(10000.0f, -(float)(2 * p) / 1024.0f);
    float pe = (d & 1) ? cosf(ang) : sinf(ang);
    float val = 2.0f * emb[(size_t)t * DMODEL + d] * 55.42562584220407f + pe; // sqrt(3072)
    o[j] = val; obv[j] = f2b(val);
  }
  *reinterpret_cast<float4*>(x + (size_t)l * DMODEL + d0) = make_float4(o[0], o[1], o[2], o[3]);
  u16x4 vb = { obv[0], obv[1], obv[2], obv[3] };
  *reinterpret_cast<u16x4*>(xb + (size_t)l * DMODEL + d0) = vb;
}

// ---------------- residual-add + LayerNorm ----------------
__global__ __launch_bounds__(256) void ln_k(const float* __restrict__ xin,
    const float* __restrict__ yin, const float* __restrict__ s, const float* __restrict__ b,
    float* __restrict__ xout, u16* __restrict__ xbout)
{
  const int row = blockIdx.x, tid = threadIdx.x;
  const int d0 = tid * 4;
  float4 xv = *reinterpret_cast<const float4*>(xin + (size_t)row * DMODEL + d0);
  float4 yv = *reinterpret_cast<const float4*>(yin + (size_t)row * DMODEL + d0);
  float t0 = xv.x + yv.x, t1 = xv.y + yv.y, t2 = xv.z + yv.z, t3 = xv.w + yv.w;
  float sum = t0 + t1 + t2 + t3;
  float sq  = t0 * t0 + t1 * t1 + t2 * t2 + t3 * t3;
#pragma unroll
  for (int d = 1; d < 64; d <<= 1) { sum += __shfl_xor(sum, d); sq += __shfl_xor(sq, d); }
  __shared__ float ssum[4], ssq[4];
  const int wid = tid >> 6;
  if ((tid & 63) == 0) { ssum[wid] = sum; ssq[wid] = sq; }
  __syncthreads();
  sum = ssum[0] + ssum[1] + ssum[2] + ssum[3];
  sq  = ssq[0] + ssq[1] + ssq[2] + ssq[3];
  const float mu = sum * (1.0f / 1024.0f);
  const float var = sq * (1.0f / 1024.0f) - mu * mu;
  const float rstd = rsqrtf(var + 1e-5f);
  float4 sv = *reinterpret_cast<const float4*>(s + d0);
  float4 bv = *reinterpret_cast<const float4*>(b + d0);
  float o0 = (t0 - mu) * rstd * sv.x + bv.x;
  float o1 = (t1 - mu) * rstd * sv.y + bv.y;
  float o2 = (t2 - mu) * rstd * sv.z + bv.z;
  float o3 = (t3 - mu) * rstd * sv.w + bv.w;
  *reinterpret_cast<float4*>(xout + (size_t)row * DMODEL + d0) = make_float4(o0, o1, o2, o3);
  u16x4 vb = { f2b(o0), f2b(o1), f2b(o2), f2b(o3) };
  *reinterpret_cast<u16x4*>(xbout + (size_t)row * DMODEL + d0) = vb;
}

// ---------------- transpose-convert: f32 in[R][C] -> bf16 out rows ----------------
__global__ __launch_bounds__(256) void tconv_k(const float* __restrict__ in, u16* __restrict__ out,
                                               int R, int C, int zper, int lstride, int obase, int zstride)
{
  __shared__ float t[64][65];
  const int rt = blockIdx.y * 64, ct = blockIdx.x * 64;
  const int z = blockIdx.z;
  in += (size_t)z * zstride;
  const int tr = threadIdx.x >> 4, tc = threadIdx.x & 15;
#pragma unroll
  for (int i = 0; i < 4; ++i) {
    int r = i * 16 + tr;
    float4 v = *reinterpret_cast<const float4*>(in + (size_t)(rt + r) * C + ct + tc * 4);
    t[r][tc * 4 + 0] = v.x; t[r][tc * 4 + 1] = v.y;
    t[r][tc * 4 + 2] = v.z; t[r][tc * 4 + 3] = v.w;
  }
  __syncthreads();
  const size_t orow0 = (size_t)(z / zper) * lstride + (size_t)(z % zper) * C + obase + ct;
#pragma unroll
  for (int i = 0; i < 4; ++i) {
    int c = i * 16 + tr;
    u16x4 o;
    o[0] = f2b(t[tc * 4 + 0][c]); o[1] = f2b(t[tc * 4 + 1][c]);
    o[2] = f2b(t[tc * 4 + 2][c]); o[3] = f2b(t[tc * 4 + 3][c]);
    *reinterpret_cast<u16x4*>(out + (orow0 + c) * R + rt + tc * 4) = o;
  }
}

// ---------------- elementwise convert f32 -> bf16 ----------------
__global__ __launch_bounds__(256) void ec_k(const float* __restrict__ in, u16* __restrict__ out)
{
  const size_t i = ((size_t)blockIdx.x * 256 + threadIdx.x) * 8;
  float4 a = *reinterpret_cast<const float4*>(in + i);
  float4 b = *reinterpret_cast<const float4*>(in + i + 4);
  short8 o;
  o[0] = f2b(a.x); o[1] = f2b(a.y); o[2] = f2b(a.z); o[3] = f2b(a.w);
  o[4] = f2b(b.x); o[5] = f2b(b.y); o[6] = f2b(b.z); o[7] = f2b(b.w);
  *reinterpret_cast<short8*>(out + i) = o;
}

// ---------------- bf16 MFMA GEMM, 2-phase double-buffered pipeline ----------------
// C[M,N] = act(A[M,K] * Bt[N,K]^T + bias); grid: x = M tiles (fastest), y = N tiles.
// BSRC 0: bf16 B^T, global_load_lds dbuf pipeline + T2 XOR swizzle (both A and B).
// BSRC 1: f32 B^T reg-staged fallback (BK=32, BN=128), classic __syncthreads loop.
// OUTMODE: 0 = f32; 1 = bf16; 2 = QKV triple bf16 [L,1024] x3
template<int BM, int BN, int BK, int BSRC, bool BIAS, bool RELU, int OUTMODE>
__global__ __launch_bounds__(256) void gemm_bt(
    const u16* __restrict__ A, int lda,
    const void* __restrict__ Bp, int ldb,
    const float* __restrict__ bias,
    void* __restrict__ Cv, int ldc, int Ktot)
{
  const int tid = threadIdx.x, lane = tid & 63, wid = tid >> 6;
  // chunked XCD swizzle (bijective: all grids are multiples of 8)
  const int nwg = gridDim.x * gridDim.y;
  const int flat = blockIdx.y * gridDim.x + blockIdx.x;
  const int qq = nwg >> 3;
  const int ni = (flat & 7) * qq + (flat >> 3);
  const int m0 = (ni % gridDim.x) * BM, n0 = (ni / gridDim.x) * BN;
  constexpr int FM = BM / 32, FN = BN / 32;
  constexpr int KS = BK / 32;
  constexpr int CPR = BK / 8;       // 16B chunks per row
  constexpr int SWM = CPR - 1;      // swizzle mask
  const int wm = (wid >> 1) * (BM / 2), wn = (wid & 1) * (BN / 2);
  f32x4 acc[FM][FN] = {};

  if constexpr (BSRC == 0) {
    __shared__ u16 As[2][BM * BK];
    __shared__ u16 Bs[2][BN * BK];
    const u16* Bt = (const u16*)Bp;

    // stage one K-tile into buffer `buf` (source pre-swizzled, LDS linear)
    auto stage = [&](int buf, int k0) {
#pragma unroll
      for (int i = 0; i < (BM * CPR) / 256; ++i) {
        int c = i * 256 + wid * 64 + lane;
        int row = c / CPR, p0 = c % CPR;
        int part = p0 ^ (row & SWM);
        gload16(A + (size_t)(m0 + row) * lda + k0 + part * 8,
                &As[buf][(i * 256 + wid * 64) * 8]);
      }
#pragma unroll
      for (int i = 0; i < (BN * CPR) / 256; ++i) {
        int c = i * 256 + wid * 64 + lane;
        int row = c / CPR, p0 = c % CPR;
        int part = p0 ^ (row & SWM);
        gload16(Bt + (size_t)(n0 + row) * ldb + k0 + part * 8,
                &Bs[buf][(i * 256 + wid * 64) * 8]);
      }
    };

    stage(0, 0);
    asm volatile("s_waitcnt vmcnt(0)" ::: "memory");
    __builtin_amdgcn_s_barrier();
    asm volatile("" ::: "memory");

    const int NT = Ktot / BK;
    int cur = 0;
    for (int t = 0; t < NT; ++t) {
      if (t + 1 < NT) stage(cur ^ 1, (t + 1) * BK);   // prefetch overlaps compute
      asm volatile("" ::: "memory");
      short8 a[KS][FM], b[KS][FN];
#pragma unroll
      for (int ks = 0; ks < KS; ++ks) {
#pragma unroll
        for (int fm = 0; fm < FM; ++fm) {
          int row = wm + fm * 16 + (lane & 15);
          int pidx = (ks * 4 + (lane >> 4)) ^ (row & SWM);
          a[ks][fm] = *reinterpret_cast<const short8*>(&As[cur][row * BK + pidx * 8]);
        }
#pragma unroll
        for (int fn = 0; fn < FN; ++fn) {
          int row = wn + fn * 16 + (lane & 15);
          int pidx = (ks * 4 + (lane >> 4)) ^ (row & SWM);
          b[ks][fn] = *reinterpret_cast<const short8*>(&Bs[cur][row * BK + pidx * 8]);
        }
      }
#pragma unroll
      for (int ks = 0; ks < KS; ++ks)
#pragma unroll
        for (int fm = 0; fm < FM; ++fm)
#pragma unroll
          for (int fn = 0; fn < FN; ++fn)
            acc[fm][fn] = mfma16(a[ks][fm], b[ks][fn], acc[fm][fn]);
      // wait for the prefetch (overlapped with the MFMAs above), then flip
      asm volatile("s_waitcnt vmcnt(0)" ::: "memory");
      __builtin_amdgcn_s_barrier();
      asm volatile("" ::: "memory");
      cur ^= 1;
    }
  } else {                       // f32 B^T fallback: BK=32, BN=128, no swizzle
    __shared__ u16 As[BM * BK];
    __shared__ u16 Bs[BN * BK];
    const float* Bf = (const float*)Bp;
    for (int k0 = 0; k0 < Ktot; k0 += BK) {
#pragma unroll
      for (int i = 0; i < (BM * CPR) / 256; ++i) {
        int c = i * 256 + wid * 64 + lane;
        int row = c / CPR, part = c % CPR;
        gload16(A + (size_t)(m0 + row) * lda + k0 + part * 8,
                &As[(i * 256 + wid * 64) * 8]);
      }
      {
        int row = tid >> 1, kh = (tid & 1) * 16;
        const float* src = Bf + (size_t)(n0 + row) * ldb + k0 + kh;
        float4 v0 = *reinterpret_cast<const float4*>(src);
        float4 v1 = *reinterpret_cast<const float4*>(src + 4);
        float4 v2 = *reinterpret_cast<const float4*>(src + 8);
        float4 v3 = *reinterpret_cast<const float4*>(src + 12);
        short8 p0, p1;
        p0[0] = f2b(v0.x); p0[1] = f2b(v0.y); p0[2] = f2b(v0.z); p0[3] = f2b(v0.w);
        p0[4] = f2b(v1.x); p0[5] = f2b(v1.y); p0[6] = f2b(v1.z); p0[7] = f2b(v1.w);
        p1[0] = f2b(v2.x); p1[1] = f2b(v2.y); p1[2] = f2b(v2.z); p1[3] = f2b(v2.w);
        p1[4] = f2b(v3.x); p1[5] = f2b(v3.y); p1[6] = f2b(v3.z); p1[7] = f2b(v3.w);
        *reinterpret_cast<short8*>(&Bs[row * BK + kh])     = p0;
        *reinterpret_cast<short8*>(&Bs[row * BK + kh + 8]) = p1;
      }
      __syncthreads();
      short8 a[KS][FM], b[KS][FN];
#pragma unroll
      for (int ks = 0; ks < KS; ++ks) {
#pragma unroll
        for (int fm = 0; fm < FM; ++fm) {
          int row = wm + fm * 16 + (lane & 15);
          a[ks][fm] = *reinterpret_cast<const short8*>(&As[row * BK + (ks * 4 + (lane >> 4)) * 8]);
        }
#pragma unroll
        for (int fn = 0; fn < FN; ++fn) {
          int row = wn + fn * 16 + (lane & 15);
          b[ks][fn] = *reinterpret_cast<const short8*>(&Bs[row * BK + (ks * 4 + (lane >> 4)) * 8]);
        }
      }
#pragma unroll
      for (int ks = 0; ks < KS; ++ks)
#pragma unroll
        for (int fm = 0; fm < FM; ++fm)
#pragma unroll
          for (int fn = 0; fn < FN; ++fn)
            acc[fm][fn] = mfma16(a[ks][fm], b[ks][fn], acc[fm][fn]);
      __syncthreads();
    }
  }

  // ---- epilogue ----
#pragma unroll
  for (int fm = 0; fm < FM; ++fm) {
#pragma unroll
    for (int fn = 0; fn < FN; ++fn) {
#pragma unroll
      for (int r = 0; r < 4; ++r) {
        int row = m0 + wm + fm * 16 + (lane >> 4) * 4 + r;
        int col = n0 + wn + fn * 16 + (lane & 15);
        float val = acc[fm][fn][r];
        if (BIAS) val += bias[col];
        if (RELU) val = fmaxf(val, 0.0f);
        if (OUTMODE == 0) {
          ((float*)Cv)[(size_t)row * ldc + col] = val;
        } else if (OUTMODE == 1) {
          ((u16*)Cv)[(size_t)row * ldc + col] = f2b(val);
        } else {
          int sel = col >> 10, cc = col & 1023;
          ((u16*)Cv)[(size_t)sel * (LSEQ * DMODEL) + (size_t)row * DMODEL + cc] = f2b(val);
        }
      }
    }
  }
}

// ---------------- causal flash attention, KVBLK=64 ----------------
__global__ __launch_bounds__(256) void attn_k(const u16* __restrict__ q,
    const u16* __restrict__ kmat, const u16* __restrict__ v, u16* __restrict__ o)
{
  __shared__ u16 Ks[64][72];
  __shared__ u16 Vt[64][72];
  __shared__ u16 Pl[4][16][72];
  const int tid = threadIdx.x, lane = tid & 63, wid = tid >> 6;
  const int h = blockIdx.y, qt = blockIdx.x;
  const int qw0 = qt * 64 + wid * 16;
  const int qrow = qw0 + (lane & 15);
  const short8 aq0 = *reinterpret_cast<const short8*>(q + (size_t)qrow * DMODEL + h * DHEAD + (lane >> 4) * 8);
  const short8 aq1 = *reinterpret_cast<const short8*>(q + (size_t)qrow * DMODEL + h * DHEAD + 32 + (lane >> 4) * 8);
  float m_run[4], l_run[4];
  f32x4 oacc[4] = {};
#pragma unroll
  for (int r = 0; r < 4; ++r) { m_run[r] = -1e30f; l_run[r] = 0.0f; }
  const int kvend = qt * 64 + 64;

  for (int kv0 = 0; kv0 < kvend; kv0 += 64) {
    {
      int kvi = tid >> 2, c16 = (tid & 3) * 16;
      const u16* kp = kmat + (size_t)(kv0 + kvi) * DMODEL + h * DHEAD + c16;
      *reinterpret_cast<short8*>(&Ks[kvi][c16])     = *reinterpret_cast<const short8*>(kp);
      *reinterpret_cast<short8*>(&Ks[kvi][c16 + 8]) = *reinterpret_cast<const short8*>(kp + 8);
      const u16* vp = v + (size_t)(kv0 + kvi) * DMODEL + h * DHEAD + c16;
      short8 v0 = *reinterpret_cast<const short8*>(vp);
      short8 v1 = *reinterpret_cast<const short8*>(vp + 8);
#pragma unroll
      for (int j = 0; j < 8; ++j) { Vt[c16 + j][kvi] = (u16)v0[j]; Vt[c16 + 8 + j][kvi] = (u16)v1[j]; }
    }
    __syncthreads();

    float sm[4][4];
#pragma unroll
    for (int t2 = 0; t2 < 4; ++t2) {
      short8 bk0 = *reinterpret_cast<const short8*>(&Ks[t2 * 16 + (lane & 15)][(lane >> 4) * 8]);
      short8 bk1 = *reinterpret_cast<const short8*>(&Ks[t2 * 16 + (lane & 15)][32 + (lane >> 4) * 8]);
      f32x4 s4 = {};
      s4 = mfma16(aq0, bk0, s4);
      s4 = mfma16(aq1, bk1, s4);
#pragma unroll
      for (int r = 0; r < 4; ++r) {
        int rowg = qw0 + (lane >> 4) * 4 + r;
        int colg = kv0 + t2 * 16 + (lane & 15);
        float val = s4[r] * 0.03125f;                 // 1/sqrt(d_model)=1/32
        sm[t2][r] = (colg <= rowg) ? val : -1e30f;
      }
    }
    float alpha[4], p[4][4];
#pragma unroll
    for (int r = 0; r < 4; ++r) {
      float mx = fmaxf(fmaxf(sm[0][r], sm[1][r]), fmaxf(sm[2][r], sm[3][r]));
#pragma unroll
      for (int d = 1; d < 16; d <<= 1) mx = fmaxf(mx, __shfl_xor(mx, d));
      float mn = fmaxf(m_run[r], mx);
      alpha[r] = __expf(m_run[r] - mn);
      float ps = 0.0f;
#pragma unroll
      for (int t2 = 0; t2 < 4; ++t2) { p[t2][r] = __expf(sm[t2][r] - mn); ps += p[t2][r]; }
#pragma unroll
      for (int d = 1; d < 16; d <<= 1) ps += __shfl_xor(ps, d);
      l_run[r] = l_run[r] * alpha[r] + ps;
      m_run[r] = mn;
    }
#pragma unroll
    for (int fn = 0; fn < 4; ++fn) {
      f32x4 t = oacc[fn];
      t[0] *= alpha[0]; t[1] *= alpha[1]; t[2] *= alpha[2]; t[3] *= alpha[3];
      oacc[fn] = t;
    }
#pragma unroll
    for (int r = 0; r < 4; ++r) {
      int rit = (lane >> 4) * 4 + r;
#pragma unroll
      for (int t2 = 0; t2 < 4; ++t2)
        Pl[wid][rit][t2 * 16 + (lane & 15)] = f2b(p[t2][r]);
    }
    short8 pa0 = *reinterpret_cast<const short8*>(&Pl[wid][lane & 15][(lane >> 4) * 8]);
    short8 pa1 = *reinterpret_cast<const short8*>(&Pl[wid][lane & 15][32 + (lane >> 4) * 8]);
#pragma unroll
    for (int fn = 0; fn < 4; ++fn) {
      short8 bv0 = *reinterpret_cast<const short8*>(&Vt[fn * 16 + (lane & 15)][(lane >> 4) * 8]);
      short8 bv1 = *reinterpret_cast<const short8*>(&Vt[fn * 16 + (lane & 15)][32 + (lane >> 4) * 8]);
      oacc[fn] = mfma16(pa0, bv0, oacc[fn]);
      oacc[fn] = mfma16(pa1, bv1, oacc[fn]);
    }
    __syncthreads();
  }
#pragma unroll
  for (int fn = 0; fn < 4; ++fn) {
#pragma unroll
    for (int r = 0; r < 4; ++r) {
      int row = qw0 + (lane >> 4) * 4 + r;
      float val = oacc[fn][r] / l_run[r];
      o[(size_t)row * DMODEL + h * DHEAD + fn * 16 + (lane & 15)] = f2b(val);
    }
  }
}

// ---------------- launch ----------------
extern "C" void kernel_launch(void* const* d_in, const int* in_sizes, int n_in,
                              void* d_out, int out_size, void* d_ws, size_t ws_size,
                              hipStream_t stream) {
  (void)in_sizes; (void)n_in; (void)out_size;
  const int*   tok    = (const int*)d_in[0];
  const float* emb    = (const float*)d_in[1];
  const float* finalb = (const float*)d_in[2];
  const float* Wq     = (const float*)d_in[3];
  const float* Wk     = (const float*)d_in[4];
  const float* Wv     = (const float*)d_in[5];
  const float* Wo     = (const float*)d_in[6];
  const float* ln1s   = (const float*)d_in[7];
  const float* ln1b   = (const float*)d_in[8];
  const float* W1     = (const float*)d_in[9];
  const float* b1     = (const float*)d_in[10];
  const float* W2     = (const float*)d_in[11];
  const float* b2     = (const float*)d_in[12];
  const float* ln2s   = (const float*)d_in[13];
  const float* ln2b   = (const float*)d_in[14];
  float* out = (float*)d_out;

  // workspace: activations
  float* x   = (float*)d_ws;                       // 4 MiB
  float* y   = x + LSEQ * DMODEL;                  // 4 MiB
  u16* xb    = (u16*)(y + LSEQ * DMODEL);
  u16* qb    = xb + LSEQ * DMODEL;
  u16* kb    = qb + LSEQ * DMODEL;
  u16* vb    = kb + LSEQ * DMODEL;
  u16* ob    = vb + LSEQ * DMODEL;
  u16* h1    = ob + LSEQ * DMODEL;                 // 8 MiB
  u16* wbase = h1 + LSEQ * DFF;

  const size_t eQKV = (size_t)3 * DMODEL * DMODEL;   // 3M u16 / layer
  const size_t eWO  = (size_t)DMODEL * DMODEL;
  const size_t eW1  = (size_t)DFF * DMODEL;
  const size_t eW2  = (size_t)DMODEL * DFF;
  const size_t perL = eQKV + eWO + eW1 + eW2;        // 12M u16 / layer
  const size_t eEMB = (size_t)NVOCAB * DMODEL;
  const size_t actE = (size_t)(wbase - (u16*)d_ws);
  const size_t bigNeed = (actE + NLAYER * perL + eEMB) * 2;
  const size_t midNeed = (actE + perL + eEMB) * 2;
  const int mode = ws_size >= bigNeed ? 2 : (ws_size >= midNeed ? 1 : 0);
  const int WL = (mode == 2) ? NLAYER : 1;           // stored layers of weights

  u16* qkvT = wbase;
  u16* woT  = qkvT + WL * eQKV;
  u16* w1T  = woT  + WL * eWO;
  u16* w2T  = w1T  + WL * eW1;
  u16* embT = w2T  + WL * eW2;

  if (mode == 2) {
    tconv_k<<<dim3(1, 16, 192), 256, 0, stream>>>(Wq, qkvT, DMODEL, DHEAD, 16, 3 * DMODEL, 0,    DMODEL * DHEAD);
    tconv_k<<<dim3(1, 16, 192), 256, 0, stream>>>(Wk, qkvT, DMODEL, DHEAD, 16, 3 * DMODEL, 1024, DMODEL * DHEAD);
    tconv_k<<<dim3(1, 16, 192), 256, 0, stream>>>(Wv, qkvT, DMODEL, DHEAD, 16, 3 * DMODEL, 2048, DMODEL * DHEAD);
    tconv_k<<<dim3(16, 16, 12), 256, 0, stream>>>(Wo, woT, DMODEL, DMODEL, 1, DMODEL, 0, DMODEL * DMODEL);
    tconv_k<<<dim3(64, 16, 12), 256, 0, stream>>>(W1, w1T, DMODEL, DFF, 1, DFF, 0, DMODEL * DFF);
    tconv_k<<<dim3(16, 64, 12), 256, 0, stream>>>(W2, w2T, DFF, DMODEL, 1, DMODEL, 0, DFF * DMODEL);
    ec_k<<<(NVOCAB * DMODEL) / 2048, 256, 0, stream>>>(emb, embT);
  } else if (mode == 1) {
    ec_k<<<(NVOCAB * DMODEL) / 2048, 256, 0, stream>>>(emb, embT);
  }

  embed_k<<<LSEQ, 256, 0, stream>>>(tok, emb, x, xb);

  for (int l = 0; l < NLAYER; ++l) {
    const float* wq  = Wq + (size_t)l * NHEAD * DMODEL * DHEAD;
    const float* wk  = Wk + (size_t)l * NHEAD * DMODEL * DHEAD;
    const float* wv  = Wv + (size_t)l * NHEAD * DMODEL * DHEAD;
    const float* wo  = Wo + (size_t)l * DMODEL * DMODEL;
    const float* w1  = W1 + (size_t)l * DMODEL * DFF;
    const float* b1l = b1 + (size_t)l * DFF;
    const float* w2  = W2 + (size_t)l * DFF * DMODEL;
    const float* b2l = b2 + (size_t)l * DMODEL;
    u16* qkvTl = qkvT + (mode == 2 ? (size_t)l * eQKV : 0);
    u16* woTl  = woT  + (mode == 2 ? (size_t)l * eWO  : 0);
    u16* w1Tl  = w1T  + (mode == 2 ? (size_t)l * eW1  : 0);
    u16* w2Tl  = w2T  + (mode == 2 ? (size_t)l * eW2  : 0);

    if (mode < 2) {   // per-layer conversion
      tconv_k<<<dim3(1, 16, 16), 256, 0, stream>>>(wq, qkvTl, DMODEL, DHEAD, 16, 0, 0,    DMODEL * DHEAD);
      tconv_k<<<dim3(1, 16, 16), 256, 0, stream>>>(wk, qkvTl, DMODEL, DHEAD, 16, 0, 1024, DMODEL * DHEAD);
      tconv_k<<<dim3(1, 16, 16), 256, 0, stream>>>(wv, qkvTl, DMODEL, DHEAD, 16, 0, 2048, DMODEL * DHEAD);
      tconv_k<<<dim3(16, 16, 1), 256, 0, stream>>>(wo, woTl, DMODEL, DMODEL, 1, 0, 0, 0);
      tconv_k<<<dim3(64, 16, 1), 256, 0, stream>>>(w1, w1Tl, DMODEL, DFF, 1, 0, 0, 0);
      tconv_k<<<dim3(16, 64, 1), 256, 0, stream>>>(w2, w2Tl, DFF, DMODEL, 1, 0, 0, 0);
    }

    gemm_bt<64, 128, 64, 0, false, false, 2><<<dim3(16, 24), 256, 0, stream>>>(
        xb, DMODEL, qkvTl, DMODEL, nullptr, qb, DMODEL, DMODEL);
    attn_k<<<dim3(16, 16), 256, 0, stream>>>(qb, kb, vb, ob);
    gemm_bt<64, 64, 64, 0, false, false, 0><<<dim3(16, 16), 256, 0, stream>>>(
        ob, DMODEL, woTl, DMODEL, nullptr, y, DMODEL, DMODEL);
    ln_k<<<LSEQ, 256, 0, stream>>>(x, y, ln1s + (size_t)l * DMODEL, ln1b + (size_t)l * DMODEL, x, xb);
    gemm_bt<64, 128, 64, 0, true, true, 1><<<dim3(16, 32), 256, 0, stream>>>(
        xb, DMODEL, w1Tl, DMODEL, b1l, h1, DFF, DMODEL);
    gemm_bt<64, 64, 64, 0, true, false, 0><<<dim3(16, 16), 256, 0, stream>>>(
        h1, DFF, w2Tl, DFF, b2l, y, DMODEL, DFF);
    ln_k<<<LSEQ, 256, 0, stream>>>(x, y, ln2s + (size_t)l * DMODEL, ln2b + (size_t)l * DMODEL, x, xb);
  }

  // logits = x @ emb^T + final_b
  if (mode >= 1) {
    gemm_bt<128, 128, 64, 0, true, false, 0><<<dim3(8, 250), 256, 0, stream>>>(
        xb, DMODEL, embT, DMODEL, finalb, out, NVOCAB, DMODEL);
  } else {
    gemm_bt<128, 128, 32, 1, true, false, 0><<<dim3(8, 250), 256, 0, stream>>>(
        xb, DMODEL, emb, DMODEL, finalb, out, NVOCAB, DMODEL);
  }
}

// Round 5
// 1950.149 us; speedup vs baseline: 1.9471x; 1.0839x over previous
//
#include <hip/hip_runtime.h>

typedef unsigned short u16;
typedef __attribute__((ext_vector_type(8))) short short8;
typedef __attribute__((ext_vector_type(4))) float f32x4;
typedef __attribute__((ext_vector_type(4))) u16 u16x4;

#define LSEQ   1024
#define DMODEL 1024
#define NHEAD  16
#define DHEAD  64
#define DFF    4096
#define NLAYER 12
#define NVOCAB 32000

__device__ __forceinline__ u16 f2b(float f) {
  union { float f; unsigned u; } x; x.f = f;
  unsigned r = x.u + 0x7fffu + ((x.u >> 16) & 1u);   // RNE
  return (u16)(r >> 16);
}

__device__ __forceinline__ f32x4 mfma16(short8 a, short8 b, f32x4 c) {
  return __builtin_amdgcn_mfma_f32_16x16x32_bf16(a, b, c, 0, 0, 0);
}

// async global->LDS, 16B per lane. LDS dest = wave-uniform base + lane*16.
__device__ __forceinline__ void gload16(const u16* g, u16* l) {
  __builtin_amdgcn_global_load_lds(
      (const __attribute__((address_space(1))) void*)g,
      (__attribute__((address_space(3))) void*)l, 16, 0, 0);
}

// ---------------- embedding + positional encoding ----------------
__global__ __launch_bounds__(256) void embed_k(const int* __restrict__ tok,
    const float* __restrict__ emb, float* __restrict__ x, u16* __restrict__ xb)
{
  const int l = blockIdx.x;
  const int d0 = threadIdx.x * 4;
  const int t = tok[l];
  const float lf = (float)l;
  float o[4]; u16 obv[4];
#pragma unroll
  for (int j = 0; j < 4; ++j) {
    int d = d0 + j;
    int p = d >> 1;
    float ang = lf * powf(10000.0f, -(float)(2 * p) / 1024.0f);
    float pe = (d & 1) ? cosf(ang) : sinf(ang);
    float val = 2.0f * emb[(size_t)t * DMODEL + d] * 55.42562584220407f + pe; // sqrt(3072)
    o[j] = val; obv[j] = f2b(val);
  }
  *reinterpret_cast<float4*>(x + (size_t)l * DMODEL + d0) = make_float4(o[0], o[1], o[2], o[3]);
  u16x4 vb = { obv[0], obv[1], obv[2], obv[3] };
  *reinterpret_cast<u16x4*>(xb + (size_t)l * DMODEL + d0) = vb;
}

// ---------------- residual-add (+P f32 partials, +opt bias) + LayerNorm ----------------
__global__ __launch_bounds__(256) void ln_k(const float* __restrict__ xin,
    const float* __restrict__ ypart, int P, const float* __restrict__ ybias,
    const float* __restrict__ s, const float* __restrict__ b,
    float* __restrict__ xout, u16* __restrict__ xbout)
{
  const int row = blockIdx.x, tid = threadIdx.x;
  const int d0 = tid * 4;
  float4 xv = *reinterpret_cast<const float4*>(xin + (size_t)row * DMODEL + d0);
  float t0 = xv.x, t1 = xv.y, t2 = xv.z, t3 = xv.w;
#pragma unroll 2
  for (int p = 0; p < P; ++p) {
    float4 yv = *reinterpret_cast<const float4*>(ypart + (size_t)p * (LSEQ * DMODEL) + (size_t)row * DMODEL + d0);
    t0 += yv.x; t1 += yv.y; t2 += yv.z; t3 += yv.w;
  }
  if (ybias) {
    float4 bb = *reinterpret_cast<const float4*>(ybias + d0);
    t0 += bb.x; t1 += bb.y; t2 += bb.z; t3 += bb.w;
  }
  float sum = t0 + t1 + t2 + t3;
  float sq  = t0 * t0 + t1 * t1 + t2 * t2 + t3 * t3;
#pragma unroll
  for (int d = 1; d < 64; d <<= 1) { sum += __shfl_xor(sum, d); sq += __shfl_xor(sq, d); }
  __shared__ float ssum[4], ssq[4];
  const int wid = tid >> 6;
  if ((tid & 63) == 0) { ssum[wid] = sum; ssq[wid] = sq; }
  __syncthreads();
  sum = ssum[0] + ssum[1] + ssum[2] + ssum[3];
  sq  = ssq[0] + ssq[1] + ssq[2] + ssq[3];
  const float mu = sum * (1.0f / 1024.0f);
  const float var = sq * (1.0f / 1024.0f) - mu * mu;
  const float rstd = rsqrtf(var + 1e-5f);
  float4 sv = *reinterpret_cast<const float4*>(s + d0);
  float4 bv = *reinterpret_cast<const float4*>(b + d0);
  float o0 = (t0 - mu) * rstd * sv.x + bv.x;
  float o1 = (t1 - mu) * rstd * sv.y + bv.y;
  float o2 = (t2 - mu) * rstd * sv.z + bv.z;
  float o3 = (t3 - mu) * rstd * sv.w + bv.w;
  *reinterpret_cast<float4*>(xout + (size_t)row * DMODEL + d0) = make_float4(o0, o1, o2, o3);
  u16x4 vb = { f2b(o0), f2b(o1), f2b(o2), f2b(o3) };
  *reinterpret_cast<u16x4*>(xbout + (size_t)row * DMODEL + d0) = vb;
}

// ---------------- transpose-convert: f32 in[R][C] -> bf16 out rows ----------------
__global__ __launch_bounds__(256) void tconv_k(const float* __restrict__ in, u16* __restrict__ out,
                                               int R, int C, int zper, int lstride, int obase, int zstride)
{
  __shared__ float t[64][65];
  const int rt = blockIdx.y * 64, ct = blockIdx.x * 64;
  const int z = blockIdx.z;
  in += (size_t)z * zstride;
  const int tr = threadIdx.x >> 4, tc = threadIdx.x & 15;
#pragma unroll
  for (int i = 0; i < 4; ++i) {
    int r = i * 16 + tr;
    float4 v = *reinterpret_cast<const float4*>(in + (size_t)(rt + r) * C + ct + tc * 4);
    t[r][tc * 4 + 0] = v.x; t[r][tc * 4 + 1] = v.y;
    t[r][tc * 4 + 2] = v.z; t[r][tc * 4 + 3] = v.w;
  }
  __syncthreads();
  const size_t orow0 = (size_t)(z / zper) * lstride + (size_t)(z % zper) * C + obase + ct;
#pragma unroll
  for (int i = 0; i < 4; ++i) {
    int c = i * 16 + tr;
    u16x4 o;
    o[0] = f2b(t[tc * 4 + 0][c]); o[1] = f2b(t[tc * 4 + 1][c]);
    o[2] = f2b(t[tc * 4 + 2][c]); o[3] = f2b(t[tc * 4 + 3][c]);
    *reinterpret_cast<u16x4*>(out + (orow0 + c) * R + rt + tc * 4) = o;
  }
}

// ---------------- elementwise convert f32 -> bf16 ----------------
__global__ __launch_bounds__(256) void ec_k(const float* __restrict__ in, u16* __restrict__ out)
{
  const size_t i = ((size_t)blockIdx.x * 256 + threadIdx.x) * 8;
  float4 a = *reinterpret_cast<const float4*>(in + i);
  float4 b = *reinterpret_cast<const float4*>(in + i + 4);
  short8 o;
  o[0] = f2b(a.x); o[1] = f2b(a.y); o[2] = f2b(a.z); o[3] = f2b(a.w);
  o[4] = f2b(b.x); o[5] = f2b(b.y); o[6] = f2b(b.z); o[7] = f2b(b.w);
  *reinterpret_cast<short8*>(out + i) = o;
}

// ---------------- bf16 MFMA GEMM, 2-phase double-buffered pipeline ----------------
// C[M,N] = act(A[M,K] * Bt[N,K]^T + bias); grid: x = M tiles, y = N tiles, z = K split.
// BSRC 0: bf16 B^T, global_load_lds dbuf pipeline + T2 XOR swizzle (both A and B).
// BSRC 1: f32 B^T reg-staged fallback (BK=32, BN=128), classic __syncthreads loop.
// OUTMODE: 0 = f32 (KSPLIT>1: partial plane per z); 1 = bf16; 2 = QKV triple bf16
template<int BM, int BN, int BK, int BSRC, bool BIAS, bool RELU, int OUTMODE, int KSPLIT>
__global__ __launch_bounds__(256) void gemm_bt(
    const u16* __restrict__ A, int lda,
    const void* __restrict__ Bp, int ldb,
    const float* __restrict__ bias,
    void* __restrict__ Cv, int ldc, int Ktot)
{
  const int tid = threadIdx.x, lane = tid & 63, wid = tid >> 6;
  // chunked XCD swizzle on (x,y) (bijective: gx*gy is a multiple of 8 in all uses)
  const int nwg = gridDim.x * gridDim.y;
  const int flat = blockIdx.y * gridDim.x + blockIdx.x;
  const int qq = nwg >> 3;
  const int ni = (flat & 7) * qq + (flat >> 3);
  const int m0 = (ni % gridDim.x) * BM, n0 = (ni / gridDim.x) * BN;
  const int kbase = (KSPLIT > 1) ? blockIdx.z * (Ktot / KSPLIT) : 0;
  const int klen  = (KSPLIT > 1) ? (Ktot / KSPLIT) : Ktot;
  constexpr int FM = BM / 32, FN = BN / 32;
  constexpr int KS = BK / 32;
  constexpr int CPR = BK / 8;       // 16B chunks per row
  constexpr int SWM = CPR - 1;      // swizzle mask
  const int wm = (wid >> 1) * (BM / 2), wn = (wid & 1) * (BN / 2);
  f32x4 acc[FM][FN] = {};

  if constexpr (BSRC == 0) {
    __shared__ u16 As[2][BM * BK];
    __shared__ u16 Bs[2][BN * BK];
    const u16* Bt = (const u16*)Bp;

    auto stage = [&](int buf, int k0) {
#pragma unroll
      for (int i = 0; i < (BM * CPR) / 256; ++i) {
        int c = i * 256 + wid * 64 + lane;
        int row = c / CPR, p0 = c % CPR;
        int part = p0 ^ (row & SWM);
        gload16(A + (size_t)(m0 + row) * lda + k0 + part * 8,
                &As[buf][(i * 256 + wid * 64) * 8]);
      }
#pragma unroll
      for (int i = 0; i < (BN * CPR) / 256; ++i) {
        int c = i * 256 + wid * 64 + lane;
        int row = c / CPR, p0 = c % CPR;
        int part = p0 ^ (row & SWM);
        gload16(Bt + (size_t)(n0 + row) * ldb + k0 + part * 8,
                &Bs[buf][(i * 256 + wid * 64) * 8]);
      }
    };

    stage(0, kbase);
    asm volatile("s_waitcnt vmcnt(0)" ::: "memory");
    __builtin_amdgcn_s_barrier();
    asm volatile("" ::: "memory");

    const int NT = klen / BK;
    int cur = 0;
    for (int t = 0; t < NT; ++t) {
      if (t + 1 < NT) stage(cur ^ 1, kbase + (t + 1) * BK);   // prefetch overlaps compute
      asm volatile("" ::: "memory");
      short8 a[KS][FM], b[KS][FN];
#pragma unroll
      for (int ks = 0; ks < KS; ++ks) {
#pragma unroll
        for (int fm = 0; fm < FM; ++fm) {
          int row = wm + fm * 16 + (lane & 15);
          int pidx = (ks * 4 + (lane >> 4)) ^ (row & SWM);
          a[ks][fm] = *reinterpret_cast<const short8*>(&As[cur][row * BK + pidx * 8]);
        }
#pragma unroll
        for (int fn = 0; fn < FN; ++fn) {
          int row = wn + fn * 16 + (lane & 15);
          int pidx = (ks * 4 + (lane >> 4)) ^ (row & SWM);
          b[ks][fn] = *reinterpret_cast<const short8*>(&Bs[cur][row * BK + pidx * 8]);
        }
      }
#pragma unroll
      for (int ks = 0; ks < KS; ++ks)
#pragma unroll
        for (int fm = 0; fm < FM; ++fm)
#pragma unroll
          for (int fn = 0; fn < FN; ++fn)
            acc[fm][fn] = mfma16(a[ks][fm], b[ks][fn], acc[fm][fn]);
      asm volatile("s_waitcnt vmcnt(0)" ::: "memory");
      __builtin_amdgcn_s_barrier();
      asm volatile("" ::: "memory");
      cur ^= 1;
    }
  } else {                       // f32 B^T fallback: BK=32, BN=128, no swizzle
    __shared__ u16 As[BM * BK];
    __shared__ u16 Bs[BN * BK];
    const float* Bf = (const float*)Bp;
    for (int k0 = 0; k0 < Ktot; k0 += BK) {
#pragma unroll
      for (int i = 0; i < (BM * CPR) / 256; ++i) {
        int c = i * 256 + wid * 64 + lane;
        int row = c / CPR, part = c % CPR;
        gload16(A + (size_t)(m0 + row) * lda + k0 + part * 8,
                &As[(i * 256 + wid * 64) * 8]);
      }
      {
        int row = tid >> 1, kh = (tid & 1) * 16;
        const float* src = Bf + (size_t)(n0 + row) * ldb + k0 + kh;
        float4 v0 = *reinterpret_cast<const float4*>(src);
        float4 v1 = *reinterpret_cast<const float4*>(src + 4);
        float4 v2 = *reinterpret_cast<const float4*>(src + 8);
        float4 v3 = *reinterpret_cast<const float4*>(src + 12);
        short8 p0, p1;
        p0[0] = f2b(v0.x); p0[1] = f2b(v0.y); p0[2] = f2b(v0.z); p0[3] = f2b(v0.w);
        p0[4] = f2b(v1.x); p0[5] = f2b(v1.y); p0[6] = f2b(v1.z); p0[7] = f2b(v1.w);
        p1[0] = f2b(v2.x); p1[1] = f2b(v2.y); p1[2] = f2b(v2.z); p1[3] = f2b(v2.w);
        p1[4] = f2b(v3.x); p1[5] = f2b(v3.y); p1[6] = f2b(v3.z); p1[7] = f2b(v3.w);
        *reinterpret_cast<short8*>(&Bs[row * BK + kh])     = p0;
        *reinterpret_cast<short8*>(&Bs[row * BK + kh + 8]) = p1;
      }
      __syncthreads();
      short8 a[KS][FM], b[KS][FN];
#pragma unroll
      for (int ks = 0; ks < KS; ++ks) {
#pragma unroll
        for (int fm = 0; fm < FM; ++fm) {
          int row = wm + fm * 16 + (lane & 15);
          a[ks][fm] = *reinterpret_cast<const short8*>(&As[row * BK + (ks * 4 + (lane >> 4)) * 8]);
        }
#pragma unroll
        for (int fn = 0; fn < FN; ++fn) {
          int row = wn + fn * 16 + (lane & 15);
          b[ks][fn] = *reinterpret_cast<const short8*>(&Bs[row * BK + (ks * 4 + (lane >> 4)) * 8]);
        }
      }
#pragma unroll
      for (int ks = 0; ks < KS; ++ks)
#pragma unroll
        for (int fm = 0; fm < FM; ++fm)
#pragma unroll
          for (int fn = 0; fn < FN; ++fn)
            acc[fm][fn] = mfma16(a[ks][fm], b[ks][fn], acc[fm][fn]);
      __syncthreads();
    }
  }

  // ---- epilogue ----
  const size_t pbase = (KSPLIT > 1) ? (size_t)blockIdx.z * gridDim.x * BM * ldc : 0;
#pragma unroll
  for (int fm = 0; fm < FM; ++fm) {
#pragma unroll
    for (int fn = 0; fn < FN; ++fn) {
#pragma unroll
      for (int r = 0; r < 4; ++r) {
        int row = m0 + wm + fm * 16 + (lane >> 4) * 4 + r;
        int col = n0 + wn + fn * 16 + (lane & 15);
        float val = acc[fm][fn][r];
        if (BIAS) val += bias[col];
        if (RELU) val = fmaxf(val, 0.0f);
        if (OUTMODE == 0) {
          ((float*)Cv)[pbase + (size_t)row * ldc + col] = val;
        } else if (OUTMODE == 1) {
          ((u16*)Cv)[(size_t)row * ldc + col] = f2b(val);
        } else {
          int sel = col >> 10, cc = col & 1023;
          ((u16*)Cv)[(size_t)sel * (LSEQ * DMODEL) + (size_t)row * DMODEL + cc] = f2b(val);
        }
      }
    }
  }
}

// ---------------- causal flash attention, KVBLK=64 ----------------
__global__ __launch_bounds__(256) void attn_k(const u16* __restrict__ q,
    const u16* __restrict__ kmat, const u16* __restrict__ v, u16* __restrict__ o)
{
  __shared__ u16 Ks[64][72];
  __shared__ u16 Vt[64][72];
  __shared__ u16 Pl[4][16][72];
  const int tid = threadIdx.x, lane = tid & 63, wid = tid >> 6;
  const int h = blockIdx.y, qt = blockIdx.x;
  const int qw0 = qt * 64 + wid * 16;
  const int qrow = qw0 + (lane & 15);
  const short8 aq0 = *reinterpret_cast<const short8*>(q + (size_t)qrow * DMODEL + h * DHEAD + (lane >> 4) * 8);
  const short8 aq1 = *reinterpret_cast<const short8*>(q + (size_t)qrow * DMODEL + h * DHEAD + 32 + (lane >> 4) * 8);
  float m_run[4], l_run[4];
  f32x4 oacc[4] = {};
#pragma unroll
  for (int r = 0; r < 4; ++r) { m_run[r] = -1e30f; l_run[r] = 0.0f; }
  const int kvend = qt * 64 + 64;

  for (int kv0 = 0; kv0 < kvend; kv0 += 64) {
    {
      int kvi = tid >> 2, c16 = (tid & 3) * 16;
      const u16* kp = kmat + (size_t)(kv0 + kvi) * DMODEL + h * DHEAD + c16;
      *reinterpret_cast<short8*>(&Ks[kvi][c16])     = *reinterpret_cast<const short8*>(kp);
      *reinterpret_cast<short8*>(&Ks[kvi][c16 + 8]) = *reinterpret_cast<const short8*>(kp + 8);
      const u16* vp = v + (size_t)(kv0 + kvi) * DMODEL + h * DHEAD + c16;
      short8 v0 = *reinterpret_cast<const short8*>(vp);
      short8 v1 = *reinterpret_cast<const short8*>(vp + 8);
#pragma unroll
      for (int j = 0; j < 8; ++j) { Vt[c16 + j][kvi] = (u16)v0[j]; Vt[c16 + 8 + j][kvi] = (u16)v1[j]; }
    }
    __syncthreads();

    float sm[4][4];
#pragma unroll
    for (int t2 = 0; t2 < 4; ++t2) {
      short8 bk0 = *reinterpret_cast<const short8*>(&Ks[t2 * 16 + (lane & 15)][(lane >> 4) * 8]);
      short8 bk1 = *reinterpret_cast<const short8*>(&Ks[t2 * 16 + (lane & 15)][32 + (lane >> 4) * 8]);
      f32x4 s4 = {};
      s4 = mfma16(aq0, bk0, s4);
      s4 = mfma16(aq1, bk1, s4);
#pragma unroll
      for (int r = 0; r < 4; ++r) {
        int rowg = qw0 + (lane >> 4) * 4 + r;
        int colg = kv0 + t2 * 16 + (lane & 15);
        float val = s4[r] * 0.03125f;                 // 1/sqrt(d_model)=1/32
        sm[t2][r] = (colg <= rowg) ? val : -1e30f;
      }
    }
    float alpha[4], p[4][4];
#pragma unroll
    for (int r = 0; r < 4; ++r) {
      float mx = fmaxf(fmaxf(sm[0][r], sm[1][r]), fmaxf(sm[2][r], sm[3][r]));
#pragma unroll
      for (int d = 1; d < 16; d <<= 1) mx = fmaxf(mx, __shfl_xor(mx, d));
      float mn = fmaxf(m_run[r], mx);
      alpha[r] = __expf(m_run[r] - mn);
      float ps = 0.0f;
#pragma unroll
      for (int t2 = 0; t2 < 4; ++t2) { p[t2][r] = __expf(sm[t2][r] - mn); ps += p[t2][r]; }
#pragma unroll
      for (int d = 1; d < 16; d <<= 1) ps += __shfl_xor(ps, d);
      l_run[r] = l_run[r] * alpha[r] + ps;
      m_run[r] = mn;
    }
#pragma unroll
    for (int fn = 0; fn < 4; ++fn) {
      f32x4 t = oacc[fn];
      t[0] *= alpha[0]; t[1] *= alpha[1]; t[2] *= alpha[2]; t[3] *= alpha[3];
      oacc[fn] = t;
    }
#pragma unroll
    for (int r = 0; r < 4; ++r) {
      int rit = (lane >> 4) * 4 + r;
#pragma unroll
      for (int t2 = 0; t2 < 4; ++t2)
        Pl[wid][rit][t2 * 16 + (lane & 15)] = f2b(p[t2][r]);
    }
    short8 pa0 = *reinterpret_cast<const short8*>(&Pl[wid][lane & 15][(lane >> 4) * 8]);
    short8 pa1 = *reinterpret_cast<const short8*>(&Pl[wid][lane & 15][32 + (lane >> 4) * 8]);
#pragma unroll
    for (int fn = 0; fn < 4; ++fn) {
      short8 bv0 = *reinterpret_cast<const short8*>(&Vt[fn * 16 + (lane & 15)][(lane >> 4) * 8]);
      short8 bv1 = *reinterpret_cast<const short8*>(&Vt[fn * 16 + (lane & 15)][32 + (lane >> 4) * 8]);
      oacc[fn] = mfma16(pa0, bv0, oacc[fn]);
      oacc[fn] = mfma16(pa1, bv1, oacc[fn]);
    }
    __syncthreads();
  }
#pragma unroll
  for (int fn = 0; fn < 4; ++fn) {
#pragma unroll
    for (int r = 0; r < 4; ++r) {
      int row = qw0 + (lane >> 4) * 4 + r;
      float val = oacc[fn][r] / l_run[r];
      o[(size_t)row * DMODEL + h * DHEAD + fn * 16 + (lane & 15)] = f2b(val);
    }
  }
}

// ---------------- launch ----------------
extern "C" void kernel_launch(void* const* d_in, const int* in_sizes, int n_in,
                              void* d_out, int out_size, void* d_ws, size_t ws_size,
                              hipStream_t stream) {
  (void)in_sizes; (void)n_in; (void)out_size;
  const int*   tok    = (const int*)d_in[0];
  const float* emb    = (const float*)d_in[1];
  const float* finalb = (const float*)d_in[2];
  const float* Wq     = (const float*)d_in[3];
  const float* Wk     = (const float*)d_in[4];
  const float* Wv     = (const float*)d_in[5];
  const float* Wo     = (const float*)d_in[6];
  const float* ln1s   = (const float*)d_in[7];
  const float* ln1b   = (const float*)d_in[8];
  const float* W1     = (const float*)d_in[9];
  const float* b1     = (const float*)d_in[10];
  const float* W2     = (const float*)d_in[11];
  const float* b2     = (const float*)d_in[12];
  const float* ln2s   = (const float*)d_in[13];
  const float* ln2b   = (const float*)d_in[14];
  float* out = (float*)d_out;

  // workspace: activations
  float* x   = (float*)d_ws;                       // 4 MiB
  float* y   = x + LSEQ * DMODEL;                  // 4 MiB (vocab fallback / scratch)
  u16* xb    = (u16*)(y + LSEQ * DMODEL);
  u16* qb    = xb + LSEQ * DMODEL;                 // qb..ob: 8 MiB contiguous
  u16* kb    = qb + LSEQ * DMODEL;
  u16* vb    = kb + LSEQ * DMODEL;
  u16* ob    = vb + LSEQ * DMODEL;
  u16* h1    = ob + LSEQ * DMODEL;                 // 8 MiB
  u16* wbase = h1 + LSEQ * DFF;
  float* woPart  = (float*)h1;   // 2 f32 planes (8 MiB) — h1 free during Wo GEMM
  float* ff2Part = (float*)qb;   // 2 f32 planes (8 MiB) — qb..ob free during FF2 GEMM

  const size_t eQKV = (size_t)3 * DMODEL * DMODEL;
  const size_t eWO  = (size_t)DMODEL * DMODEL;
  const size_t eW1  = (size_t)DFF * DMODEL;
  const size_t eW2  = (size_t)DMODEL * DFF;
  const size_t perL = eQKV + eWO + eW1 + eW2;
  const size_t eEMB = (size_t)NVOCAB * DMODEL;
  const size_t actE = (size_t)(wbase - (u16*)d_ws);
  const size_t bigNeed = (actE + NLAYER * perL + eEMB) * 2;
  const size_t midNeed = (actE + perL + eEMB) * 2;
  const int mode = ws_size >= bigNeed ? 2 : (ws_size >= midNeed ? 1 : 0);
  const int WL = (mode == 2) ? NLAYER : 1;

  u16* qkvT = wbase;
  u16* woT  = qkvT + WL * eQKV;
  u16* w1T  = woT  + WL * eWO;
  u16* w2T  = w1T  + WL * eW1;
  u16* embT = w2T  + WL * eW2;

  if (mode == 2) {
    tconv_k<<<dim3(1, 16, 192), 256, 0, stream>>>(Wq, qkvT, DMODEL, DHEAD, 16, 3 * DMODEL, 0,    DMODEL * DHEAD);
    tconv_k<<<dim3(1, 16, 192), 256, 0, stream>>>(Wk, qkvT, DMODEL, DHEAD, 16, 3 * DMODEL, 1024, DMODEL * DHEAD);
    tconv_k<<<dim3(1, 16, 192), 256, 0, stream>>>(Wv, qkvT, DMODEL, DHEAD, 16, 3 * DMODEL, 2048, DMODEL * DHEAD);
    tconv_k<<<dim3(16, 16, 12), 256, 0, stream>>>(Wo, woT, DMODEL, DMODEL, 1, DMODEL, 0, DMODEL * DMODEL);
    tconv_k<<<dim3(64, 16, 12), 256, 0, stream>>>(W1, w1T, DMODEL, DFF, 1, DFF, 0, DMODEL * DFF);
    tconv_k<<<dim3(16, 64, 12), 256, 0, stream>>>(W2, w2T, DFF, DMODEL, 1, DMODEL, 0, DFF * DMODEL);
    ec_k<<<(NVOCAB * DMODEL) / 2048, 256, 0, stream>>>(emb, embT);
  } else if (mode == 1) {
    ec_k<<<(NVOCAB * DMODEL) / 2048, 256, 0, stream>>>(emb, embT);
  }

  embed_k<<<LSEQ, 256, 0, stream>>>(tok, emb, x, xb);

  for (int l = 0; l < NLAYER; ++l) {
    const float* wq  = Wq + (size_t)l * NHEAD * DMODEL * DHEAD;
    const float* wk  = Wk + (size_t)l * NHEAD * DMODEL * DHEAD;
    const float* wv  = Wv + (size_t)l * NHEAD * DMODEL * DHEAD;
    const float* wo  = Wo + (size_t)l * DMODEL * DMODEL;
    const float* w1  = W1 + (size_t)l * DMODEL * DFF;
    const float* b1l = b1 + (size_t)l * DFF;
    const float* w2  = W2 + (size_t)l * DFF * DMODEL;
    const float* b2l = b2 + (size_t)l * DMODEL;
    u16* qkvTl = qkvT + (mode == 2 ? (size_t)l * eQKV : 0);
    u16* woTl  = woT  + (mode == 2 ? (size_t)l * eWO  : 0);
    u16* w1Tl  = w1T  + (mode == 2 ? (size_t)l * eW1  : 0);
    u16* w2Tl  = w2T  + (mode == 2 ? (size_t)l * eW2  : 0);

    if (mode < 2) {
      tconv_k<<<dim3(1, 16, 16), 256, 0, stream>>>(wq, qkvTl, DMODEL, DHEAD, 16, 0, 0,    DMODEL * DHEAD);
      tconv_k<<<dim3(1, 16, 16), 256, 0, stream>>>(wk, qkvTl, DMODEL, DHEAD, 16, 0, 1024, DMODEL * DHEAD);
      tconv_k<<<dim3(1, 16, 16), 256, 0, stream>>>(wv, qkvTl, DMODEL, DHEAD, 16, 0, 2048, DMODEL * DHEAD);
      tconv_k<<<dim3(16, 16, 1), 256, 0, stream>>>(wo, woTl, DMODEL, DMODEL, 1, 0, 0, 0);
      tconv_k<<<dim3(64, 16, 1), 256, 0, stream>>>(w1, w1Tl, DMODEL, DFF, 1, 0, 0, 0);
      tconv_k<<<dim3(16, 64, 1), 256, 0, stream>>>(w2, w2Tl, DFF, DMODEL, 1, 0, 0, 0);
    }

    // QKV: 128x128 tile, full K  (grid 8x24 = 192)
    gemm_bt<128, 128, 64, 0, false, false, 2, 1><<<dim3(8, 24), 256, 0, stream>>>(
        xb, DMODEL, qkvTl, DMODEL, nullptr, qb, DMODEL, DMODEL);
    attn_k<<<dim3(16, 16), 256, 0, stream>>>(qb, kb, vb, ob);
    // Wo: 128x64 tile, split-K 2 (grid 8x16x2 = 256), partials -> h1 region
    gemm_bt<128, 64, 64, 0, false, false, 0, 2><<<dim3(8, 16, 2), 256, 0, stream>>>(
        ob, DMODEL, woTl, DMODEL, nullptr, woPart, DMODEL, DMODEL);
    ln_k<<<LSEQ, 256, 0, stream>>>(x, woPart, 2, nullptr,
        ln1s + (size_t)l * DMODEL, ln1b + (size_t)l * DMODEL, x, xb);
    // FF1: 128x128 tile, full K (grid 8x32 = 256), bias+relu, bf16 out
    gemm_bt<128, 128, 64, 0, true, true, 1, 1><<<dim3(8, 32), 256, 0, stream>>>(
        xb, DMODEL, w1Tl, DMODEL, b1l, h1, DFF, DMODEL);
    // FF2: 128x64 tile, split-K 2 (grid 8x16x2 = 256), partials -> qb region; bias in ln_k
    gemm_bt<128, 64, 64, 0, false, false, 0, 2><<<dim3(8, 16, 2), 256, 0, stream>>>(
        h1, DFF, w2Tl, DFF, nullptr, ff2Part, DMODEL, DFF);
    ln_k<<<LSEQ, 256, 0, stream>>>(x, ff2Part, 2, b2l,
        ln2s + (size_t)l * DMODEL, ln2b + (size_t)l * DMODEL, x, xb);
  }

  // logits = x @ emb^T + final_b
  if (mode >= 1) {
    gemm_bt<128, 128, 64, 0, true, false, 0, 1><<<dim3(8, 250), 256, 0, stream>>>(
        xb, DMODEL, embT, DMODEL, finalb, out, NVOCAB, DMODEL);
  } else {
    gemm_bt<128, 128, 32, 1, true, false, 0, 1><<<dim3(8, 250), 256, 0, stream>>>(
        xb, DMODEL, emb, DMODEL, finalb, out, NVOCAB, DMODEL);
  }
}

// Round 6
// 1933.020 us; speedup vs baseline: 1.9644x; 1.0089x over previous
//
#include <hip/hip_runtime.h>

typedef unsigned short u16;
typedef __attribute__((ext_vector_type(8))) short short8;
typedef __attribute__((ext_vector_type(4))) float f32x4;
typedef __attribute__((ext_vector_type(4))) u16 u16x4;

#define LSEQ   1024
#define DMODEL 1024
#define NHEAD  16
#define DHEAD  64
#define DFF    4096
#define NLAYER 12
#define NVOCAB 32000

__device__ __forceinline__ u16 f2b(float f) {
  union { float f; unsigned u; } x; x.f = f;
  unsigned r = x.u + 0x7fffu + ((x.u >> 16) & 1u);   // RNE
  return (u16)(r >> 16);
}

__device__ __forceinline__ f32x4 mfma16(short8 a, short8 b, f32x4 c) {
  return __builtin_amdgcn_mfma_f32_16x16x32_bf16(a, b, c, 0, 0, 0);
}

// async global->LDS, 16B per lane. LDS dest = wave-uniform base + lane*16.
__device__ __forceinline__ void gload16(const u16* g, u16* l) {
  __builtin_amdgcn_global_load_lds(
      (const __attribute__((address_space(1))) void*)g,
      (__attribute__((address_space(3))) void*)l, 16, 0, 0);
}

// ---------------- embedding + positional encoding ----------------
__global__ __launch_bounds__(256) void embed_k(const int* __restrict__ tok,
    const float* __restrict__ emb, float* __restrict__ x, u16* __restrict__ xb)
{
  const int l = blockIdx.x;
  const int d0 = threadIdx.x * 4;
  const int t = tok[l];
  const float lf = (float)l;
  float o[4]; u16 obv[4];
#pragma unroll
  for (int j = 0; j < 4; ++j) {
    int d = d0 + j;
    int p = d >> 1;
    float ang = lf * powf(10000.0f, -(float)(2 * p) / 1024.0f);
    float pe = (d & 1) ? cosf(ang) : sinf(ang);
    float val = 2.0f * emb[(size_t)t * DMODEL + d] * 55.42562584220407f + pe; // sqrt(3072)
    o[j] = val; obv[j] = f2b(val);
  }
  *reinterpret_cast<float4*>(x + (size_t)l * DMODEL + d0) = make_float4(o[0], o[1], o[2], o[3]);
  u16x4 vb = { obv[0], obv[1], obv[2], obv[3] };
  *reinterpret_cast<u16x4*>(xb + (size_t)l * DMODEL + d0) = vb;
}

// ---------------- residual-add (+P f32 partials, +opt bias) + LayerNorm ----------------
__global__ __launch_bounds__(256) void ln_k(const float* __restrict__ xin,
    const float* __restrict__ ypart, int P, const float* __restrict__ ybias,
    const float* __restrict__ s, const float* __restrict__ b,
    float* __restrict__ xout, u16* __restrict__ xbout)
{
  const int row = blockIdx.x, tid = threadIdx.x;
  const int d0 = tid * 4;
  float4 xv = *reinterpret_cast<const float4*>(xin + (size_t)row * DMODEL + d0);
  float t0 = xv.x, t1 = xv.y, t2 = xv.z, t3 = xv.w;
#pragma unroll 2
  for (int p = 0; p < P; ++p) {
    float4 yv = *reinterpret_cast<const float4*>(ypart + (size_t)p * (LSEQ * DMODEL) + (size_t)row * DMODEL + d0);
    t0 += yv.x; t1 += yv.y; t2 += yv.z; t3 += yv.w;
  }
  if (ybias) {
    float4 bb = *reinterpret_cast<const float4*>(ybias + d0);
    t0 += bb.x; t1 += bb.y; t2 += bb.z; t3 += bb.w;
  }
  float sum = t0 + t1 + t2 + t3;
  float sq  = t0 * t0 + t1 * t1 + t2 * t2 + t3 * t3;
#pragma unroll
  for (int d = 1; d < 64; d <<= 1) { sum += __shfl_xor(sum, d); sq += __shfl_xor(sq, d); }
  __shared__ float ssum[4], ssq[4];
  const int wid = tid >> 6;
  if ((tid & 63) == 0) { ssum[wid] = sum; ssq[wid] = sq; }
  __syncthreads();
  sum = ssum[0] + ssum[1] + ssum[2] + ssum[3];
  sq  = ssq[0] + ssq[1] + ssq[2] + ssq[3];
  const float mu = sum * (1.0f / 1024.0f);
  const float var = sq * (1.0f / 1024.0f) - mu * mu;
  const float rstd = rsqrtf(var + 1e-5f);
  float4 sv = *reinterpret_cast<const float4*>(s + d0);
  float4 bv = *reinterpret_cast<const float4*>(b + d0);
  float o0 = (t0 - mu) * rstd * sv.x + bv.x;
  float o1 = (t1 - mu) * rstd * sv.y + bv.y;
  float o2 = (t2 - mu) * rstd * sv.z + bv.z;
  float o3 = (t3 - mu) * rstd * sv.w + bv.w;
  *reinterpret_cast<float4*>(xout + (size_t)row * DMODEL + d0) = make_float4(o0, o1, o2, o3);
  u16x4 vb = { f2b(o0), f2b(o1), f2b(o2), f2b(o3) };
  *reinterpret_cast<u16x4*>(xbout + (size_t)row * DMODEL + d0) = vb;
}

// ---------------- transpose-convert: f32 in[R][C] -> bf16 out rows ----------------
__global__ __launch_bounds__(256) void tconv_k(const float* __restrict__ in, u16* __restrict__ out,
                                               int R, int C, int zper, int lstride, int obase, int zstride)
{
  __shared__ float t[64][65];
  const int rt = blockIdx.y * 64, ct = blockIdx.x * 64;
  const int z = blockIdx.z;
  in += (size_t)z * zstride;
  const int tr = threadIdx.x >> 4, tc = threadIdx.x & 15;
#pragma unroll
  for (int i = 0; i < 4; ++i) {
    int r = i * 16 + tr;
    float4 v = *reinterpret_cast<const float4*>(in + (size_t)(rt + r) * C + ct + tc * 4);
    t[r][tc * 4 + 0] = v.x; t[r][tc * 4 + 1] = v.y;
    t[r][tc * 4 + 2] = v.z; t[r][tc * 4 + 3] = v.w;
  }
  __syncthreads();
  const size_t orow0 = (size_t)(z / zper) * lstride + (size_t)(z % zper) * C + obase + ct;
#pragma unroll
  for (int i = 0; i < 4; ++i) {
    int c = i * 16 + tr;
    u16x4 o;
    o[0] = f2b(t[tc * 4 + 0][c]); o[1] = f2b(t[tc * 4 + 1][c]);
    o[2] = f2b(t[tc * 4 + 2][c]); o[3] = f2b(t[tc * 4 + 3][c]);
    *reinterpret_cast<u16x4*>(out + (orow0 + c) * R + rt + tc * 4) = o;
  }
}

// ---------------- elementwise convert f32 -> bf16 ----------------
__global__ __launch_bounds__(256) void ec_k(const float* __restrict__ in, u16* __restrict__ out)
{
  const size_t i = ((size_t)blockIdx.x * 256 + threadIdx.x) * 8;
  float4 a = *reinterpret_cast<const float4*>(in + i);
  float4 b = *reinterpret_cast<const float4*>(in + i + 4);
  short8 o;
  o[0] = f2b(a.x); o[1] = f2b(a.y); o[2] = f2b(a.z); o[3] = f2b(a.w);
  o[4] = f2b(b.x); o[5] = f2b(b.y); o[6] = f2b(b.z); o[7] = f2b(b.w);
  *reinterpret_cast<short8*>(out + i) = o;
}

// ---------------- bf16 MFMA GEMM, 3-stage counted-vmcnt pipeline ----------------
// C[M,N] = act(A[M,K] * Bt[N,K]^T + bias); grid: x = M tiles, y = N tiles, z = K split.
// BSRC 0: bf16 B^T, 3 LDS slots, global_load_lds, counted vmcnt(4) (T4) + XOR swizzle (T2).
// BSRC 1: f32 B^T reg-staged fallback (BK must be 32, BN 128), classic loop (slot 0 only).
// OUTMODE: 0 = f32 (KSPLIT>1: partial plane per z); 1 = bf16; 2 = QKV triple bf16
// Loads/thread/tile = (BM+BN)*BK/8/256 = 4 for all instantiations (vmcnt constant).
template<int BM, int BN, int BK, int BSRC, bool BIAS, bool RELU, int OUTMODE, int KSPLIT>
__global__ __launch_bounds__(256) void gemm_bt(
    const u16* __restrict__ A, int lda,
    const void* __restrict__ Bp, int ldb,
    const float* __restrict__ bias,
    void* __restrict__ Cv, int ldc, int Ktot)
{
  static_assert((BM * BK) / 8 == 512 && (BN * BK) / 8 == 512, "4 loads/thread/tile");
  __shared__ u16 As[3][BM * BK];
  __shared__ u16 Bs[3][BN * BK];
  const int tid = threadIdx.x, lane = tid & 63, wid = tid >> 6;
  // chunked XCD swizzle on (x,y) (bijective: gx*gy is a multiple of 8 in all uses)
  const int nwg = gridDim.x * gridDim.y;
  const int flat = blockIdx.y * gridDim.x + blockIdx.x;
  const int qq = nwg >> 3;
  const int ni = (flat & 7) * qq + (flat >> 3);
  const int m0 = (ni % gridDim.x) * BM, n0 = (ni / gridDim.x) * BN;
  const int kbase = (KSPLIT > 1) ? blockIdx.z * (Ktot / KSPLIT) : 0;
  const int klen  = (KSPLIT > 1) ? (Ktot / KSPLIT) : Ktot;
  constexpr int FM = BM / 32, FN = BN / 32;
  constexpr int KS = BK / 32;
  constexpr int CPR = BK / 8;       // 16B chunks per row
  constexpr int SWM = CPR - 1;      // swizzle mask
  const int wm = (wid >> 1) * (BM / 2), wn = (wid & 1) * (BN / 2);
  f32x4 acc[FM][FN] = {};

  if constexpr (BSRC == 0) {
    const u16* Bt = (const u16*)Bp;
    auto stage = [&](int slot, int k0) {
#pragma unroll
      for (int i = 0; i < 2; ++i) {
        int c = i * 256 + wid * 64 + lane;
        int row = c / CPR, p0 = c % CPR;
        int part = p0 ^ (row & SWM);
        gload16(A + (size_t)(m0 + row) * lda + k0 + part * 8,
                &As[slot][(i * 256 + wid * 64) * 8]);
      }
#pragma unroll
      for (int i = 0; i < 2; ++i) {
        int c = i * 256 + wid * 64 + lane;
        int row = c / CPR, p0 = c % CPR;
        int part = p0 ^ (row & SWM);
        gload16(Bt + (size_t)(n0 + row) * ldb + k0 + part * 8,
                &Bs[slot][(i * 256 + wid * 64) * 8]);
      }
    };

    const int NT = klen / BK;
    stage(0, kbase);
    stage(1, kbase + BK);
    asm volatile("s_waitcnt vmcnt(4)" ::: "memory");   // tile 0 landed, tile 1 in flight
    __builtin_amdgcn_s_barrier();
    asm volatile("" ::: "memory");

    int cur = 0, stg = 2;
    for (int t = 0; t < NT; ++t) {
      const bool more = (t + 2 < NT);
      if (more) stage(stg, kbase + (t + 2) * BK);      // tile t+2 issued; stays in flight
      asm volatile("" ::: "memory");
      short8 a[KS][FM], b[KS][FN];
#pragma unroll
      for (int ks = 0; ks < KS; ++ks) {
#pragma unroll
        for (int fm = 0; fm < FM; ++fm) {
          int row = wm + fm * 16 + (lane & 15);
          int pidx = (ks * 4 + (lane >> 4)) ^ (row & SWM);
          a[ks][fm] = *reinterpret_cast<const short8*>(&As[cur][row * BK + pidx * 8]);
        }
#pragma unroll
        for (int fn = 0; fn < FN; ++fn) {
          int row = wn + fn * 16 + (lane & 15);
          int pidx = (ks * 4 + (lane >> 4)) ^ (row & SWM);
          b[ks][fn] = *reinterpret_cast<const short8*>(&Bs[cur][row * BK + pidx * 8]);
        }
      }
#pragma unroll
      for (int ks = 0; ks < KS; ++ks)
#pragma unroll
        for (int fm = 0; fm < FM; ++fm)
#pragma unroll
          for (int fn = 0; fn < FN; ++fn)
            acc[fm][fn] = mfma16(a[ks][fm], b[ks][fn], acc[fm][fn]);
      // counted wait: tile t+1 landed; tile t+2 (4 loads) stays in flight across barrier
      if (more) asm volatile("s_waitcnt vmcnt(4)" ::: "memory");
      else      asm volatile("s_waitcnt vmcnt(0)" ::: "memory");
      __builtin_amdgcn_s_barrier();
      asm volatile("" ::: "memory");
      cur = (cur == 2) ? 0 : cur + 1;
      stg = (stg == 2) ? 0 : stg + 1;
    }
  } else {                       // f32 B^T fallback: BK=32, BN=128, slot 0 only
    const float* Bf = (const float*)Bp;
    for (int k0 = 0; k0 < Ktot; k0 += BK) {
#pragma unroll
      for (int i = 0; i < 2; ++i) {
        int c = i * 256 + wid * 64 + lane;
        int row = c / CPR, part = c % CPR;
        gload16(A + (size_t)(m0 + row) * lda + k0 + part * 8,
                &As[0][(i * 256 + wid * 64) * 8]);
      }
      {
        int row = tid >> 1, kh = (tid & 1) * 16;
        const float* src = Bf + (size_t)(n0 + row) * ldb + k0 + kh;
        float4 v0 = *reinterpret_cast<const float4*>(src);
        float4 v1 = *reinterpret_cast<const float4*>(src + 4);
        float4 v2 = *reinterpret_cast<const float4*>(src + 8);
        float4 v3 = *reinterpret_cast<const float4*>(src + 12);
        short8 p0, p1;
        p0[0] = f2b(v0.x); p0[1] = f2b(v0.y); p0[2] = f2b(v0.z); p0[3] = f2b(v0.w);
        p0[4] = f2b(v1.x); p0[5] = f2b(v1.y); p0[6] = f2b(v1.z); p0[7] = f2b(v1.w);
        p1[0] = f2b(v2.x); p1[1] = f2b(v2.y); p1[2] = f2b(v2.z); p1[3] = f2b(v2.w);
        p1[4] = f2b(v3.x); p1[5] = f2b(v3.y); p1[6] = f2b(v3.z); p1[7] = f2b(v3.w);
        *reinterpret_cast<short8*>(&Bs[0][row * BK + kh])     = p0;
        *reinterpret_cast<short8*>(&Bs[0][row * BK + kh + 8]) = p1;
      }
      __syncthreads();
      short8 a[KS][FM], b[KS][FN];
#pragma unroll
      for (int ks = 0; ks < KS; ++ks) {
#pragma unroll
        for (int fm = 0; fm < FM; ++fm) {
          int row = wm + fm * 16 + (lane & 15);
          a[ks][fm] = *reinterpret_cast<const short8*>(&As[0][row * BK + (ks * 4 + (lane >> 4)) * 8]);
        }
#pragma unroll
        for (int fn = 0; fn < FN; ++fn) {
          int row = wn + fn * 16 + (lane & 15);
          b[ks][fn] = *reinterpret_cast<const short8*>(&Bs[0][row * BK + (ks * 4 + (lane >> 4)) * 8]);
        }
      }
#pragma unroll
      for (int ks = 0; ks < KS; ++ks)
#pragma unroll
        for (int fm = 0; fm < FM; ++fm)
#pragma unroll
          for (int fn = 0; fn < FN; ++fn)
            acc[fm][fn] = mfma16(a[ks][fm], b[ks][fn], acc[fm][fn]);
      __syncthreads();
    }
  }

  // ---- epilogue ----
  const size_t pbase = (KSPLIT > 1) ? (size_t)blockIdx.z * gridDim.x * BM * ldc : 0;
#pragma unroll
  for (int fm = 0; fm < FM; ++fm) {
#pragma unroll
    for (int fn = 0; fn < FN; ++fn) {
#pragma unroll
      for (int r = 0; r < 4; ++r) {
        int row = m0 + wm + fm * 16 + (lane >> 4) * 4 + r;
        int col = n0 + wn + fn * 16 + (lane & 15);
        float val = acc[fm][fn][r];
        if (BIAS) val += bias[col];
        if (RELU) val = fmaxf(val, 0.0f);
        if (OUTMODE == 0) {
          ((float*)Cv)[pbase + (size_t)row * ldc + col] = val;
        } else if (OUTMODE == 1) {
          ((u16*)Cv)[(size_t)row * ldc + col] = f2b(val);
        } else {
          int sel = col >> 10, cc = col & 1023;
          ((u16*)Cv)[(size_t)sel * (LSEQ * DMODEL) + (size_t)row * DMODEL + cc] = f2b(val);
        }
      }
    }
  }
}

// ---------------- causal flash attention, KVBLK=64 ----------------
__global__ __launch_bounds__(256) void attn_k(const u16* __restrict__ q,
    const u16* __restrict__ kmat, const u16* __restrict__ v, u16* __restrict__ o)
{
  __shared__ u16 Ks[64][72];
  __shared__ u16 Vt[64][72];
  __shared__ u16 Pl[4][16][72];
  const int tid = threadIdx.x, lane = tid & 63, wid = tid >> 6;
  const int h = blockIdx.y, qt = blockIdx.x;
  const int qw0 = qt * 64 + wid * 16;
  const int qrow = qw0 + (lane & 15);
  const short8 aq0 = *reinterpret_cast<const short8*>(q + (size_t)qrow * DMODEL + h * DHEAD + (lane >> 4) * 8);
  const short8 aq1 = *reinterpret_cast<const short8*>(q + (size_t)qrow * DMODEL + h * DHEAD + 32 + (lane >> 4) * 8);
  float m_run[4], l_run[4];
  f32x4 oacc[4] = {};
#pragma unroll
  for (int r = 0; r < 4; ++r) { m_run[r] = -1e30f; l_run[r] = 0.0f; }
  const int kvend = qt * 64 + 64;

  for (int kv0 = 0; kv0 < kvend; kv0 += 64) {
    {
      int kvi = tid >> 2, c16 = (tid & 3) * 16;
      const u16* kp = kmat + (size_t)(kv0 + kvi) * DMODEL + h * DHEAD + c16;
      *reinterpret_cast<short8*>(&Ks[kvi][c16])     = *reinterpret_cast<const short8*>(kp);
      *reinterpret_cast<short8*>(&Ks[kvi][c16 + 8]) = *reinterpret_cast<const short8*>(kp + 8);
      const u16* vp = v + (size_t)(kv0 + kvi) * DMODEL + h * DHEAD + c16;
      short8 v0 = *reinterpret_cast<const short8*>(vp);
      short8 v1 = *reinterpret_cast<const short8*>(vp + 8);
#pragma unroll
      for (int j = 0; j < 8; ++j) { Vt[c16 + j][kvi] = (u16)v0[j]; Vt[c16 + 8 + j][kvi] = (u16)v1[j]; }
    }
    __syncthreads();

    float sm[4][4];
#pragma unroll
    for (int t2 = 0; t2 < 4; ++t2) {
      short8 bk0 = *reinterpret_cast<const short8*>(&Ks[t2 * 16 + (lane & 15)][(lane >> 4) * 8]);
      short8 bk1 = *reinterpret_cast<const short8*>(&Ks[t2 * 16 + (lane & 15)][32 + (lane >> 4) * 8]);
      f32x4 s4 = {};
      s4 = mfma16(aq0, bk0, s4);
      s4 = mfma16(aq1, bk1, s4);
#pragma unroll
      for (int r = 0; r < 4; ++r) {
        int rowg = qw0 + (lane >> 4) * 4 + r;
        int colg = kv0 + t2 * 16 + (lane & 15);
        float val = s4[r] * 0.03125f;                 // 1/sqrt(d_model)=1/32
        sm[t2][r] = (colg <= rowg) ? val : -1e30f;
      }
    }
    float alpha[4], p[4][4];
#pragma unroll
    for (int r = 0; r < 4; ++r) {
      float mx = fmaxf(fmaxf(sm[0][r], sm[1][r]), fmaxf(sm[2][r], sm[3][r]));
#pragma unroll
      for (int d = 1; d < 16; d <<= 1) mx = fmaxf(mx, __shfl_xor(mx, d));
      float mn = fmaxf(m_run[r], mx);
      alpha[r] = __expf(m_run[r] - mn);
      float ps = 0.0f;
#pragma unroll
      for (int t2 = 0; t2 < 4; ++t2) { p[t2][r] = __expf(sm[t2][r] - mn); ps += p[t2][r]; }
#pragma unroll
      for (int d = 1; d < 16; d <<= 1) ps += __shfl_xor(ps, d);
      l_run[r] = l_run[r] * alpha[r] + ps;
      m_run[r] = mn;
    }
#pragma unroll
    for (int fn = 0; fn < 4; ++fn) {
      f32x4 t = oacc[fn];
      t[0] *= alpha[0]; t[1] *= alpha[1]; t[2] *= alpha[2]; t[3] *= alpha[3];
      oacc[fn] = t;
    }
#pragma unroll
    for (int r = 0; r < 4; ++r) {
      int rit = (lane >> 4) * 4 + r;
#pragma unroll
      for (int t2 = 0; t2 < 4; ++t2)
        Pl[wid][rit][t2 * 16 + (lane & 15)] = f2b(p[t2][r]);
    }
    short8 pa0 = *reinterpret_cast<const short8*>(&Pl[wid][lane & 15][(lane >> 4) * 8]);
    short8 pa1 = *reinterpret_cast<const short8*>(&Pl[wid][lane & 15][32 + (lane >> 4) * 8]);
#pragma unroll
    for (int fn = 0; fn < 4; ++fn) {
      short8 bv0 = *reinterpret_cast<const short8*>(&Vt[fn * 16 + (lane & 15)][(lane >> 4) * 8]);
      short8 bv1 = *reinterpret_cast<const short8*>(&Vt[fn * 16 + (lane & 15)][32 + (lane >> 4) * 8]);
      oacc[fn] = mfma16(pa0, bv0, oacc[fn]);
      oacc[fn] = mfma16(pa1, bv1, oacc[fn]);
    }
    __syncthreads();
  }
#pragma unroll
  for (int fn = 0; fn < 4; ++fn) {
#pragma unroll
    for (int r = 0; r < 4; ++r) {
      int row = qw0 + (lane >> 4) * 4 + r;
      float val = oacc[fn][r] / l_run[r];
      o[(size_t)row * DMODEL + h * DHEAD + fn * 16 + (lane & 15)] = f2b(val);
    }
  }
}

// ---------------- launch ----------------
extern "C" void kernel_launch(void* const* d_in, const int* in_sizes, int n_in,
                              void* d_out, int out_size, void* d_ws, size_t ws_size,
                              hipStream_t stream) {
  (void)in_sizes; (void)n_in; (void)out_size;
  const int*   tok    = (const int*)d_in[0];
  const float* emb    = (const float*)d_in[1];
  const float* finalb = (const float*)d_in[2];
  const float* Wq     = (const float*)d_in[3];
  const float* Wk     = (const float*)d_in[4];
  const float* Wv     = (const float*)d_in[5];
  const float* Wo     = (const float*)d_in[6];
  const float* ln1s   = (const float*)d_in[7];
  const float* ln1b   = (const float*)d_in[8];
  const float* W1     = (const float*)d_in[9];
  const float* b1     = (const float*)d_in[10];
  const float* W2     = (const float*)d_in[11];
  const float* b2     = (const float*)d_in[12];
  const float* ln2s   = (const float*)d_in[13];
  const float* ln2b   = (const float*)d_in[14];
  float* out = (float*)d_out;

  // workspace: activations
  float* x   = (float*)d_ws;                       // 4 MiB
  float* y   = x + LSEQ * DMODEL;                  // 4 MiB (scratch)
  u16* xb    = (u16*)(y + LSEQ * DMODEL);
  u16* qb    = xb + LSEQ * DMODEL;                 // qb..ob: 8 MiB contiguous
  u16* kb    = qb + LSEQ * DMODEL;
  u16* vb    = kb + LSEQ * DMODEL;
  u16* ob    = vb + LSEQ * DMODEL;
  u16* h1    = ob + LSEQ * DMODEL;                 // 8 MiB
  u16* wbase = h1 + LSEQ * DFF;
  float* woPart  = (float*)h1;   // 2 f32 planes (8 MiB) — h1 free during Wo GEMM
  float* ff2Part = (float*)qb;   // 2 f32 planes (8 MiB) — qb..ob free during FF2 GEMM

  const size_t eQKV = (size_t)3 * DMODEL * DMODEL;
  const size_t eWO  = (size_t)DMODEL * DMODEL;
  const size_t eW1  = (size_t)DFF * DMODEL;
  const size_t eW2  = (size_t)DMODEL * DFF;
  const size_t perL = eQKV + eWO + eW1 + eW2;
  const size_t eEMB = (size_t)NVOCAB * DMODEL;
  const size_t actE = (size_t)(wbase - (u16*)d_ws);
  const size_t bigNeed = (actE + NLAYER * perL + eEMB) * 2;
  const size_t midNeed = (actE + perL + eEMB) * 2;
  const int mode = ws_size >= bigNeed ? 2 : (ws_size >= midNeed ? 1 : 0);
  const int WL = (mode == 2) ? NLAYER : 1;

  u16* qkvT = wbase;
  u16* woT  = qkvT + WL * eQKV;
  u16* w1T  = woT  + WL * eWO;
  u16* w2T  = w1T  + WL * eW1;
  u16* embT = w2T  + WL * eW2;

  if (mode == 2) {
    tconv_k<<<dim3(1, 16, 192), 256, 0, stream>>>(Wq, qkvT, DMODEL, DHEAD, 16, 3 * DMODEL, 0,    DMODEL * DHEAD);
    tconv_k<<<dim3(1, 16, 192), 256, 0, stream>>>(Wk, qkvT, DMODEL, DHEAD, 16, 3 * DMODEL, 1024, DMODEL * DHEAD);
    tconv_k<<<dim3(1, 16, 192), 256, 0, stream>>>(Wv, qkvT, DMODEL, DHEAD, 16, 3 * DMODEL, 2048, DMODEL * DHEAD);
    tconv_k<<<dim3(16, 16, 12), 256, 0, stream>>>(Wo, woT, DMODEL, DMODEL, 1, DMODEL, 0, DMODEL * DMODEL);
    tconv_k<<<dim3(64, 16, 12), 256, 0, stream>>>(W1, w1T, DMODEL, DFF, 1, DFF, 0, DMODEL * DFF);
    tconv_k<<<dim3(16, 64, 12), 256, 0, stream>>>(W2, w2T, DFF, DMODEL, 1, DMODEL, 0, DFF * DMODEL);
    ec_k<<<(NVOCAB * DMODEL) / 2048, 256, 0, stream>>>(emb, embT);
  } else if (mode == 1) {
    ec_k<<<(NVOCAB * DMODEL) / 2048, 256, 0, stream>>>(emb, embT);
  }

  embed_k<<<LSEQ, 256, 0, stream>>>(tok, emb, x, xb);

  for (int l = 0; l < NLAYER; ++l) {
    const float* wq  = Wq + (size_t)l * NHEAD * DMODEL * DHEAD;
    const float* wk  = Wk + (size_t)l * NHEAD * DMODEL * DHEAD;
    const float* wv  = Wv + (size_t)l * NHEAD * DMODEL * DHEAD;
    const float* wo  = Wo + (size_t)l * DMODEL * DMODEL;
    const float* w1  = W1 + (size_t)l * DMODEL * DFF;
    const float* b1l = b1 + (size_t)l * DFF;
    const float* w2  = W2 + (size_t)l * DFF * DMODEL;
    const float* b2l = b2 + (size_t)l * DMODEL;
    u16* qkvTl = qkvT + (mode == 2 ? (size_t)l * eQKV : 0);
    u16* woTl  = woT  + (mode == 2 ? (size_t)l * eWO  : 0);
    u16* w1Tl  = w1T  + (mode == 2 ? (size_t)l * eW1  : 0);
    u16* w2Tl  = w2T  + (mode == 2 ? (size_t)l * eW2  : 0);

    if (mode < 2) {
      tconv_k<<<dim3(1, 16, 16), 256, 0, stream>>>(wq, qkvTl, DMODEL, DHEAD, 16, 0, 0,    DMODEL * DHEAD);
      tconv_k<<<dim3(1, 16, 16), 256, 0, stream>>>(wk, qkvTl, DMODEL, DHEAD, 16, 0, 1024, DMODEL * DHEAD);
      tconv_k<<<dim3(1, 16, 16), 256, 0, stream>>>(wv, qkvTl, DMODEL, DHEAD, 16, 0, 2048, DMODEL * DHEAD);
      tconv_k<<<dim3(16, 16, 1), 256, 0, stream>>>(wo, woTl, DMODEL, DMODEL, 1, 0, 0, 0);
      tconv_k<<<dim3(64, 16, 1), 256, 0, stream>>>(w1, w1Tl, DMODEL, DFF, 1, 0, 0, 0);
      tconv_k<<<dim3(16, 64, 1), 256, 0, stream>>>(w2, w2Tl, DFF, DMODEL, 1, 0, 0, 0);
    }

    // QKV: 64x64 tiles (grid 16x48 = 768 blocks, ~3/CU)
    gemm_bt<64, 64, 64, 0, false, false, 2, 1><<<dim3(16, 48), 256, 0, stream>>>(
        xb, DMODEL, qkvTl, DMODEL, nullptr, qb, DMODEL, DMODEL);
    attn_k<<<dim3(16, 16), 256, 0, stream>>>(qb, kb, vb, ob);
    // Wo: 64x64, split-K 2 (grid 16x16x2 = 512 blocks), partials -> h1 region
    gemm_bt<64, 64, 64, 0, false, false, 0, 2><<<dim3(16, 16, 2), 256, 0, stream>>>(
        ob, DMODEL, woTl, DMODEL, nullptr, woPart, DMODEL, DMODEL);
    ln_k<<<LSEQ, 256, 0, stream>>>(x, woPart, 2, nullptr,
        ln1s + (size_t)l * DMODEL, ln1b + (size_t)l * DMODEL, x, xb);
    // FF1: 64x64 (grid 16x64 = 1024 blocks), bias+relu, bf16 out
    gemm_bt<64, 64, 64, 0, true, true, 1, 1><<<dim3(16, 64), 256, 0, stream>>>(
        xb, DMODEL, w1Tl, DMODEL, b1l, h1, DFF, DMODEL);
    // FF2: 64x64, split-K 2 (grid 16x16x2 = 512 blocks), partials -> qb region; bias in ln_k
    gemm_bt<64, 64, 64, 0, false, false, 0, 2><<<dim3(16, 16, 2), 256, 0, stream>>>(
        h1, DFF, w2Tl, DFF, nullptr, ff2Part, DMODEL, DFF);
    ln_k<<<LSEQ, 256, 0, stream>>>(x, ff2Part, 2, b2l,
        ln2s + (size_t)l * DMODEL, ln2b + (size_t)l * DMODEL, x, xb);
  }

  // logits = x @ emb^T + final_b  (128x128, BK=32: 48KB LDS -> 3 blocks/CU, 2000 blocks)
  if (mode >= 1) {
    gemm_bt<128, 128, 32, 0, true, false, 0, 1><<<dim3(8, 250), 256, 0, stream>>>(
        xb, DMODEL, embT, DMODEL, finalb, out, NVOCAB, DMODEL);
  } else {
    gemm_bt<128, 128, 32, 1, true, false, 0, 1><<<dim3(8, 250), 256, 0, stream>>>(
        xb, DMODEL, emb, DMODEL, finalb, out, NVOCAB, DMODEL);
  }
}